// Round 6
// baseline (1152.462 us; speedup 1.0000x reference)
//
#include <hip/hip_runtime.h>
#include <hip/hip_bf16.h>

#define DEV __device__ __forceinline__

// ---------------- problem constants (fixed by setup_inputs) ----------------
constexpr int Nn   = 65536;        // num_ent
constexpr int Ee   = 262144;       // edges
constexpr int Rr   = 200;          // relation_num
constexpr int BQ   = 40;           // batch queries
constexpr int Rt   = Rr * BQ;      // 8000
constexpr int Hh   = 64;
constexpr int SHOT = 5;
constexpr float SLOPE  = 0.22916667f;   // (1/8 + 1/3)/2
constexpr float EPS_LN = 1e-5f;

// ---------------- workspace layout (float offsets); ws[0..15] = flag block ----
constexpr size_t BASE = 16;
constexpr size_t off_node   = BASE;                              // bf16 Nn*64
constexpr size_t off_node2  = off_node  + (size_t)Nn*32;         // bf16 accum
constexpr size_t off_rel    = off_node2 + (size_t)Nn*32;         // bf16 Rt*64
constexpr size_t off_rel2   = off_rel   + (size_t)Rt*32;         // bf16 accum
constexpr size_t off_fin    = off_rel2  + (size_t)Rt*32;         // fp32, 3 slabs
constexpr size_t off_finln  = off_fin   + (size_t)3*Rt*Hh;
constexpr size_t off_loop   = off_finln + (size_t)Rt*Hh;
constexpr size_t off_avP    = off_loop  + (size_t)BQ*Hh;         // Ee (permuted order)
constexpr size_t off_bvP    = off_avP   + (size_t)Ee;
constexpr size_t off_asum   = off_bvP   + (size_t)Ee;
constexpr size_t off_bsum   = off_asum  + (size_t)Nn;            // contiguous after asum
constexpr size_t off_deg    = off_bsum  + (size_t)Rt;
constexpr size_t off_uv     = off_deg   + (size_t)Nn;            // 4*Rt
constexpr size_t off_colP   = off_uv    + (size_t)4*Rt;          // int, permuted
constexpr size_t off_rowP   = off_colP  + (size_t)Ee;
constexpr size_t off_etP    = off_rowP  + (size_t)Ee;
constexpr size_t off_eqrP   = off_etP   + (size_t)Ee;
constexpr size_t off_cf1    = off_eqrP  + (size_t)Ee;            // per-edge coeff msg1
constexpr size_t off_cf2    = off_cf1   + (size_t)Ee;            // per-edge coeff msg2
constexpr size_t off_hist   = off_cf2   + (size_t)Ee;            // 256 ints
constexpr size_t off_base   = off_hist  + 256;                   // 256 ints
constexpr size_t off_Went   = off_base  + 256;
constexpr size_t off_Wrel   = off_Went  + (size_t)3*64*64;
constexpr size_t off_Wfin   = off_Wrel  + (size_t)3*64*64;
constexpr size_t off_Wloop  = off_Wfin  + (size_t)192*64;
constexpr size_t off_bmsg   = off_Wloop + (size_t)3*128*64;
constexpr size_t off_bht2r  = off_bmsg  + 192;
constexpr size_t off_bent   = off_bht2r + 192;
constexpr size_t off_brel   = off_bent  + 192;
constexpr size_t off_bloop  = off_brel  + 192;
constexpr size_t off_bfin   = off_bloop + 192;
constexpr size_t off_Wa     = off_bfin  + 64;
constexpr size_t off_ba     = off_Wa    + 384;
constexpr size_t off_Wb     = off_ba    + 4;
constexpr size_t off_bb     = off_Wb    + 384;
constexpr size_t off_pos    = off_bb    + 4;
constexpr size_t off_srel   = off_pos   + 1024;
constexpr size_t off_loop0  = off_srel  + 64;
constexpr size_t off_WmsgF  = off_loop0 + 64;                    // bf16 frags (u16)
constexpr size_t off_Wht2rF = off_WmsgF + 18432;
constexpr size_t off_end    = off_Wht2rF + 18432;

typedef __attribute__((ext_vector_type(8))) short short8v;
typedef __attribute__((ext_vector_type(4))) float float4v;

DEV float bf2f(unsigned short u) { return __uint_as_float(((unsigned)u) << 16); }
DEV unsigned short f2bf_rtne(float f) {
    unsigned int b = __float_as_uint(f);
    b += 0x7FFFu + ((b >> 16) & 1u);
    return (unsigned short)(b >> 16);
}
DEV float actf(float x) { return x >= 0.f ? x : x * SLOPE; }
DEV void atomAddF(float* p, float v) {
#if defined(__HIP_DEVICE_COMPILE__)
    unsafeAtomicAdd(p, v);
#endif
}
DEV void atomPkAddBf16(unsigned short* p, unsigned int pk) {
#if defined(__HIP_DEVICE_COMPILE__)
    asm volatile("global_atomic_pk_add_bf16 %0, %1, off"
                 :: "v"((unsigned long long)p), "v"(pk) : "memory");
#endif
}
DEV float loadF(const void* p, size_t i, int isb) {
    return isb ? bf2f(((const unsigned short*)p)[i]) : ((const float*)p)[i];
}

// ============================ dtype sniff ============================
__global__ __launch_bounds__(64) void k_sniff(const unsigned short* __restrict__ pos, int* __restrict__ flag) {
    float v = bf2f(pos[threadIdx.x]);
    bool bad = !(fabsf(v) < 1e3f);
    unsigned long long m = __ballot(bad);
    if (threadIdx.x == 0) flag[0] = (m == 0ull) ? 1 : 0;   // 1 = bf16, 0 = f32
}

__global__ __launch_bounds__(256) void k_fill16(unsigned short* __restrict__ out, int n, unsigned short val) {
    int i = blockIdx.x * 256 + threadIdx.x;
    if (i < n) out[i] = val;
}

// ============================ weight prep (+ zeroing) ============================
struct PrepArgs { const void* src[19]; void* dst[19]; };

__global__ __launch_bounds__(256) void k_prep(PrepArgs a, const int* __restrict__ flag,
                                              int* __restrict__ degi, unsigned int* __restrict__ relz,
                                              int* __restrict__ hist) {
    constexpr int NJ = 19;
    constexpr int type[NJ] = {3,3,1,1,1,2, 0,0,0,0,0,0,0,0,0,0,0,0,0};
    constexpr int KD[NJ]   = {192,192,64,64,192,128, 0,0,0,0,0,0,0,0,0,0,0,0,0};
    constexpr int NEL[NJ]  = {36864,36864,12288,12288,12288,24576,
                              192,192,192,192,192,64,384,3,384,3,1024,64,64};
    const int isb = flag[0];
    int tid0 = blockIdx.x * blockDim.x + threadIdx.x;
    int stride = gridDim.x * blockDim.x;
    for (int j = 0; j < NJ; ++j) {
        const void* s = a.src[j];
        int n = NEL[j];
        if (type[j] == 0) {
            float* d = (float*)a.dst[j];
            for (int i = tid0; i < n; i += stride) d[i] = loadF(s, i, isb);
        } else if (type[j] == 1) {
            float* d = (float*)a.dst[j];
            int K = KD[j];
            for (int i = tid0; i < n; i += stride) {
                int hh = i & 15;
                int k  = (i >> 4) % K;
                int rest = i / (16 * K);
                int wv = rest & 3, b = rest >> 2;
                d[i] = loadF(s, (size_t)(b*64 + wv*16 + hh) * K + k, isb);
            }
        } else if (type[j] == 2) {
            float* d = (float*)a.dst[j];
            int K = KD[j];
            for (int i = tid0; i < n; i += stride) {
                int h = i & 63;
                int k = (i >> 6) % K;
                int b = i / (64 * K);
                d[i] = loadF(s, (size_t)(b*64 + h) * K + k, isb);
            }
        } else {
            unsigned short* d = (unsigned short*)a.dst[j];
            for (int i = tid0; i < n; i += stride) {
                int layer = i / 12288;
                int r1 = i % 12288;
                int c  = r1 / 2048;
                int r2 = r1 % 2048;
                int g  = r2 / 512;
                int r3 = r2 % 512;
                int l  = r3 >> 3;
                int jj = r3 & 7;
                int nn = g * 16 + (l & 15);
                int k  = c * 32 + (l >> 4) * 8 + jj;
                d[i] = f2bf_rtne(loadF(s, (size_t)layer * 12288 + (size_t)nn * 192 + k, isb));
            }
        }
    }
    for (int i = tid0; i < Nn; i += stride) degi[i] = 0;
    for (int i = tid0; i < Rt * 32; i += stride) relz[i] = 0u;
    for (int i = tid0; i < 256; i += stride) hist[i] = 0;
}

// ============================ degree + bucket histogram ============================
__global__ __launch_bounds__(256) void k_count_deg(const int* __restrict__ rowp, const int* __restrict__ col,
                                                   int* __restrict__ degi, int* __restrict__ hist) {
    int e = blockIdx.x * 256 + threadIdx.x;
    if (e < Ee) {
        atomicAdd(&degi[rowp[e]], 1);
        atomicAdd(&hist[col[e] >> 8], 1);
    }
}
// deg -> deg^-1/2 in place; block 0 also scans hist -> base (exclusive)
__global__ __launch_bounds__(256) void k_deg_inv(int* __restrict__ degi,
                                                 const int* __restrict__ hist, int* __restrict__ base) {
    int n = blockIdx.x * 256 + threadIdx.x;
    if (n < Nn) {
        int d = degi[n];
        float r = d > 0 ? 1.0f / sqrtf((float)d) : 0.0f;
        ((float*)degi)[n] = r;
    }
    if (blockIdx.x == 0) {
        __shared__ int sh[256];
        int t = threadIdx.x;
        int v = hist[t];
        sh[t] = v; __syncthreads();
        for (int o = 1; o < 256; o <<= 1) {
            int u = (t >= o) ? sh[t - o] : 0;
            __syncthreads();
            sh[t] += u;
            __syncthreads();
        }
        base[t] = sh[t] - v;                 // exclusive prefix
    }
}

// node token init + counting-sort scatter (base ready from previous dispatch)
__global__ __launch_bounds__(256) void k_node_init(const int* __restrict__ labels,
                                                   const float* __restrict__ posf,
                                                   unsigned short* __restrict__ node,
                                                   const int* __restrict__ col, const int* __restrict__ rowp,
                                                   const int* __restrict__ et, const int* __restrict__ eqr,
                                                   int* __restrict__ base,
                                                   int* __restrict__ colP, int* __restrict__ rowP,
                                                   int* __restrict__ etP, int* __restrict__ eqrP) {
    int idx = blockIdx.x * 256 + threadIdx.x;
    if (idx < Nn * Hh) {
        int n = idx >> 6, h = idx & 63;
        int pos = labels[2*n] * 4 + labels[2*n + 1];
        node[idx] = f2bf_rtne(posf[pos * 64 + h]);
    }
    if (idx < Ee) {
        int c = col[idx];
        int slot = atomicAdd(&base[c >> 8], 1);
        colP[slot] = c; rowP[slot] = rowp[idx];
        etP[slot] = et[idx]; eqrP[slot] = eqr[idx];
    }
}

// merged small inits: h-rows (skip if also a t-row: t wins, ref order), t-rows, rel rows, loop
__global__ __launch_bounds__(256) void k_init_small(const int* __restrict__ hpos, const int* __restrict__ tpos,
                                                    const int* __restrict__ qrel,
                                                    const float* __restrict__ posf,
                                                    const float* __restrict__ srel,
                                                    const float* __restrict__ l0,
                                                    unsigned short* __restrict__ node,
                                                    unsigned short* __restrict__ rel,
                                                    float* __restrict__ loop) {
    int idx = blockIdx.x * 256 + threadIdx.x;
    int seg = idx / (BQ * Hh), r = idx % (BQ * Hh);
    int b = r >> 6, h = r & 63;
    if (seg == 0) {
        int p = hpos[b];
        bool skip = false;
        for (int j = 0; j < BQ; ++j) skip |= (tpos[j] == p);
        if (!skip) node[(size_t)p * 64 + h] = f2bf_rtne(posf[h]);
    } else if (seg == 1) {
        node[(size_t)tpos[b] * 64 + h] = f2bf_rtne(posf[64 + h]);
    } else if (seg == 2) {
        rel[((size_t)qrel[b] + (size_t)b * Rr) * 64 + h] = f2bf_rtne(srel[h]);
    } else if (seg == 3) {
        loop[r] = l0[h];
    }
}

// ============================ per-relation alpha/beta factors + zeroing ============================
__global__ __launch_bounds__(256) void k_uv(const unsigned short* __restrict__ rel,
                                            const float* __restrict__ Wa, const float* __restrict__ Wb,
                                            float* __restrict__ uv,
                                            float* __restrict__ asum,      // asum+bsum contiguous
                                            float4v* __restrict__ node2, float4v* __restrict__ rel2) {
    int tid = threadIdx.x, lane = tid & 63, wv = tid >> 6;
    int w = blockIdx.x * 4 + wv;
    if (w < Rt) {
        float x = bf2f(rel[(size_t)w * 64 + lane]);
        float ax = actf(x);
        float pua = ax * Wa[lane], pva = ax * Wa[64 + lane];
        float pub = x * Wb[lane],  pvb = x * Wb[64 + lane];
        for (int off = 32; off; off >>= 1) {
            pua += __shfl_xor(pua, off); pva += __shfl_xor(pva, off);
            pub += __shfl_xor(pub, off); pvb += __shfl_xor(pvb, off);
        }
        if (lane == 0) {
            uv[w] = pua; uv[Rt + w] = pva; uv[2 * Rt + w] = pub; uv[3 * Rt + w] = pvb;
        }
    }
    int tid0 = blockIdx.x * 256 + tid;
    int stride = gridDim.x * 256;
    float4v z = {0.f, 0.f, 0.f, 0.f};
    for (int i = tid0; i < Nn + Rt; i += stride) asum[i] = 0.f;
    for (int i = tid0; i < Nn * 8; i += stride) node2[i] = z;
    for (int i = tid0; i < Rt * 8; i += stride) rel2[i] = z;
}

// per-edge (permuted order) alpha/beta values + segment sums
__global__ __launch_bounds__(256) void k_ab_edge(const int* __restrict__ etP, const int* __restrict__ eqrP,
                                                 const int* __restrict__ rowP,
                                                 const float* __restrict__ uv,
                                                 const float* __restrict__ ba, const float* __restrict__ bb,
                                                 float* __restrict__ avP, float* __restrict__ bvP,
                                                 float* __restrict__ a_sum, float* __restrict__ b_sum) {
    int e = blockIdx.x * 256 + threadIdx.x;
    if (e >= Ee) return;
    int t = etP[e], q = eqrP[e];
    float av = expf(uv[t] + uv[Rt + q] + ba[0]);
    float bv = expf(uv[2 * Rt + t] + uv[3 * Rt + q] + bb[0]);
    avP[e] = av; bvP[e] = bv;
    atomAddF(&a_sum[rowP[e]], av);
    atomAddF(&b_sum[t], bv);
}

// per-edge final coefficients (absorbs the chained double-index gathers)
__global__ __launch_bounds__(256) void k_coeff(const int* __restrict__ colP, const int* __restrict__ rowP,
                                               const int* __restrict__ etP,
                                               const int* __restrict__ rowp_orig, const int* __restrict__ et_orig,
                                               const float* __restrict__ avP, const float* __restrict__ bvP,
                                               const float* __restrict__ asum, const float* __restrict__ bsum,
                                               const float* __restrict__ deg,
                                               float* __restrict__ cf1, float* __restrict__ cf2) {
    int i = blockIdx.x * 256 + threadIdx.x;
    if (i >= Ee) return;
    int r = rowP[i], c = colP[i], t = etP[i];
    float dn = deg[r] * deg[c];
    cf1[i] = avP[i] / (asum[rowp_orig[r]] + 1e-10f) * dn * dn;   // faithful double index + norm twice
    cf2[i] = bvP[i] / (bsum[et_orig[t]] + 1e-10f);               // faithful double index
}

// ============================ MFMA edge message kernel ============================
template<int KIND>   // 0 = msg1 (h/r/q -> node_new[row]), 1 = msg2 (h/t/q -> rel_new[et])
__global__ __launch_bounds__(256) void k_msg_mfma(
    const unsigned short* __restrict__ node, const unsigned short* __restrict__ rel,
    const int* __restrict__ colP, const int* __restrict__ rowP,
    const int* __restrict__ etP, const int* __restrict__ eqrP,
    const unsigned short* __restrict__ Wfrag,   // [6][4][64][8] bf16 (this layer)
    const float* __restrict__ bias,             // [64] fp32
    const float* __restrict__ cf,               // per-edge coefficient (precomputed)
    unsigned short* __restrict__ dst)           // bf16 accumulator table
{
    constexpr int P = 200;
    __shared__ __align__(16) unsigned short feat[64 * P];
    __shared__ int s_src0[64], s_src1[64], s_src2[64], s_dst[64];
    __shared__ float s_coeff[64];
    const int tid = threadIdx.x;
    const int lane = tid & 63;
    const int wv = tid >> 6;
    const int e0 = blockIdx.x * 64;

    if (tid < 64) {
        int e = e0 + tid;
        s_src0[tid] = colP[e];
        s_src1[tid] = (KIND == 0) ? etP[e] : rowP[e];
        s_src2[tid] = eqrP[e];
        s_dst[tid]  = (KIND == 0) ? rowP[e] : etP[e];
        s_coeff[tid] = cf[e];
    }

    const int wr = wv >> 1, wc = wv & 1;
    short8v bf[2][6];
#pragma unroll
    for (int tc = 0; tc < 2; ++tc) {
        int g = wc * 2 + tc;
#pragma unroll
        for (int c = 0; c < 6; ++c)
            bf[tc][c] = *(const short8v*)(Wfrag + (((size_t)c * 4 + g) * 64 + lane) * 8);
    }
    __syncthreads();

    // gather 192 bf16 rows (64 edges x 3 parts), 8 lanes/row x dwordx4
    {
        const int sub = lane >> 3, ls8 = lane & 7;
#pragma unroll
        for (int t2 = 0; t2 < 6; ++t2) {
            int unit = wv * 48 + t2 * 8 + sub;      // unit = part*64 + e
            int e = unit & 63, part = unit >> 6;
            int srow = part == 0 ? s_src0[e] : (part == 1 ? s_src1[e] : s_src2[e]);
            const unsigned short* base;
            if (KIND == 0) base = (part == 0) ? node : rel;
            else           base = (part == 2) ? rel : node;
            uint4 v = *(const uint4*)(base + (size_t)srow * 64 + ls8 * 8);
            *(uint4*)(feat + (size_t)e * P + part * 64 + ls8 * 8) = v;
        }
    }
    __syncthreads();

    const int m = lane & 15, qd = lane >> 4;
    float4v zero = {0.f, 0.f, 0.f, 0.f};
    float4v acc[2][2];
    acc[0][0] = zero; acc[0][1] = zero; acc[1][0] = zero; acc[1][1] = zero;
#pragma unroll
    for (int c = 0; c < 6; ++c) {
        short8v a0 = *(const short8v*)(feat + (wr * 32 + m) * P + c * 32 + qd * 8);
        short8v a1 = *(const short8v*)(feat + (wr * 32 + 16 + m) * P + c * 32 + qd * 8);
        acc[0][0] = __builtin_amdgcn_mfma_f32_16x16x32_bf16(a0, bf[0][c], acc[0][0], 0, 0, 0);
        acc[0][1] = __builtin_amdgcn_mfma_f32_16x16x32_bf16(a0, bf[1][c], acc[0][1], 0, 0, 0);
        acc[1][0] = __builtin_amdgcn_mfma_f32_16x16x32_bf16(a1, bf[0][c], acc[1][0], 0, 0, 0);
        acc[1][1] = __builtin_amdgcn_mfma_f32_16x16x32_bf16(a1, bf[1][c], acc[1][1], 0, 0, 0);
    }

#pragma unroll
    for (int tc = 0; tc < 2; ++tc) {
        int h = wc * 32 + tc * 16 + m;              // C/D: col = lane&15
        float bi = bias[h];
#pragma unroll
        for (int tr = 0; tr < 2; ++tr) {
#pragma unroll
            for (int r = 0; r < 4; ++r) {           // C/D: row = (lane>>4)*4 + reg
                int er = wr * 32 + tr * 16 + qd * 4 + r;
                float v = actf(acc[tr][tc][r] + bi) * s_coeff[er];
                float vn = __shfl_xor(v, 1);
                if (!(lane & 1)) {
                    unsigned int pk = (unsigned int)f2bf_rtne(v)
                                    | ((unsigned int)f2bf_rtne(vn) << 16);
                    atomPkAddBf16(dst + (size_t)s_dst[er] * 64 + h, pk);
                }
            }
        }
    }
#if defined(__HIP_DEVICE_COMPILE__)
    asm volatile("s_waitcnt vmcnt(0)" ::: "memory");
#endif
}

// ============================ row-wise 64x64 transform + LN ============================
__global__ __launch_bounds__(256) void k_ent_ln(const unsigned short* __restrict__ x,
                                                const float* __restrict__ Wv,
                                                const float* __restrict__ bias,
                                                unsigned short* __restrict__ out) {
    __shared__ float xT[64 * 65];
    int tid = threadIdx.x, lane = tid & 63;
    int wv = tid >> 6;
    size_t n0 = (size_t)blockIdx.x * 64;
    for (int j = wv; j < 64; j += 4) xT[lane * 65 + j] = bf2f(x[(n0 + j) * 64 + lane]);
    __syncthreads();
    float acc[16];
#pragma unroll
    for (int h = 0; h < 16; ++h) acc[h] = 0.f;
    const float* Wl = Wv + wv * (64 * 16);
    for (int k = 0; k < 64; ++k) {
        float f = xT[k * 65 + lane];
        const float* wr = Wl + k * 16;
#pragma unroll
        for (int hh = 0; hh < 16; ++hh) acc[hh] = fmaf(f, wr[hh], acc[hh]);
    }
    __syncthreads();
    float* yT = xT;
#pragma unroll
    for (int hh = 0; hh < 16; ++hh) {
        int h = wv * 16 + hh;
        yT[h * 65 + lane] = actf(acc[hh] + bias[h]);
    }
    __syncthreads();
    for (int jj = 0; jj < 16; ++jj) {
        int j = wv * 16 + jj;
        float v = yT[lane * 65 + j];
        float s = v, s2 = v * v;
        for (int off = 32; off; off >>= 1) { s += __shfl_xor(s, off); s2 += __shfl_xor(s2, off); }
        float mean = s * (1.f / 64.f);
        float var = s2 * (1.f / 64.f) - mean * mean;
        if (var < 0.f) var = 0.f;
        out[(n0 + j) * 64 + lane] = f2bf_rtne((v - mean) / sqrtf(var + EPS_LN));
    }
}

__global__ __launch_bounds__(256) void k_rel_ln(const unsigned short* __restrict__ x,
                                                const float* __restrict__ Wv, const float* __restrict__ bias,
                                                unsigned short* __restrict__ rel,
                                                float* __restrict__ fin_i) {
    __shared__ float xT[64 * 65];
    int tid = threadIdx.x, lane = tid & 63;
    int wv = tid >> 6;
    size_t r0 = (size_t)blockIdx.x * 64;
    for (int j = wv; j < 64; j += 4) xT[lane * 65 + j] = bf2f(x[(r0 + j) * 64 + lane]);
    __syncthreads();
    float acc[16];
#pragma unroll
    for (int h = 0; h < 16; ++h) acc[h] = 0.f;
    const float* Wl = Wv + wv * (64 * 16);
    for (int k = 0; k < 64; ++k) {
        float f = xT[k * 65 + lane];
        const float* wr = Wl + k * 16;
#pragma unroll
        for (int hh = 0; hh < 16; ++hh) acc[hh] = fmaf(f, wr[hh], acc[hh]);
    }
    __syncthreads();
    float* yT = xT;
#pragma unroll
    for (int hh = 0; hh < 16; ++hh) {
        int h = wv * 16 + hh;
        yT[h * 65 + lane] = actf(acc[hh] + bias[h]);
    }
    __syncthreads();
    for (int jj = 0; jj < 16; ++jj) {
        int j = wv * 16 + jj;
        float v = yT[lane * 65 + j] + bf2f(rel[(r0 + j) * 64 + lane]);
        float s = v, s2 = v * v;
        for (int off = 32; off; off >>= 1) { s += __shfl_xor(s, off); s2 += __shfl_xor(s2, off); }
        float mean = s * (1.f / 64.f);
        float var = s2 * (1.f / 64.f) - mean * mean;
        if (var < 0.f) var = 0.f;
        float nv = (v - mean) / sqrtf(var + EPS_LN);
        rel[(r0 + j) * 64 + lane] = f2bf_rtne(nv);
        fin_i[(r0 + j) * 64 + lane] = nv;
    }
}

__global__ __launch_bounds__(64) void k_loop_upd(const unsigned short* __restrict__ rel,
                                                 const int* __restrict__ qrel,
                                                 const float* __restrict__ Wt,
                                                 const float* __restrict__ bias,
                                                 float* __restrict__ loop) {
    __shared__ float cat[128];
    int b = blockIdx.x, lane = threadIdx.x;
    float lv = loop[b * 64 + lane];
    int qr = qrel[b] + b * Rr;
    cat[lane] = lv;
    cat[64 + lane] = bf2f(rel[(size_t)qr * 64 + lane]);
    __syncthreads();
    float acc = 0.f;
    for (int k = 0; k < 128; ++k) acc = fmaf(cat[k], Wt[k * 64 + lane], acc);
    float v = lv + actf(acc + bias[lane]);
    float s = v, s2 = v * v;
    for (int off = 32; off; off >>= 1) { s += __shfl_xor(s, off); s2 += __shfl_xor(s2, off); }
    float mean = s * (1.f / 64.f);
    float var = s2 * (1.f / 64.f) - mean * mean;
    if (var < 0.f) var = 0.f;
    loop[b * 64 + lane] = (v - mean) / sqrtf(var + EPS_LN);
}

// ============================ final projection + LN ============================
__global__ __launch_bounds__(256) void k_final(const float* __restrict__ finals,
                                               const float* __restrict__ Wv,
                                               const float* __restrict__ bias,
                                               float* __restrict__ fin_ln) {
    __shared__ float featT[192 * 65];
    int tid = threadIdx.x, lane = tid & 63;
    int wv = tid >> 6;
    size_t r0 = (size_t)blockIdx.x * 64;
    for (int j = wv; j < 192; j += 4) {
        int e = j / 3, part = j - e * 3;
        featT[(part * 64 + lane) * 65 + e] = finals[(size_t)part * Rt * 64 + (r0 + e) * 64 + lane];
    }
    __syncthreads();
    float acc[16];
#pragma unroll
    for (int h = 0; h < 16; ++h) acc[h] = 0.f;
    const float* Wl = Wv + wv * (192 * 16);
    for (int k = 0; k < 192; ++k) {
        float f = featT[k * 65 + lane];
        const float* wr = Wl + k * 16;
#pragma unroll
        for (int hh = 0; hh < 16; ++hh) acc[hh] = fmaf(f, wr[hh], acc[hh]);
    }
    __syncthreads();
    float* yT = featT;
#pragma unroll
    for (int hh = 0; hh < 16; ++hh) {
        int h = wv * 16 + hh;
        yT[h * 65 + lane] = actf(acc[hh] + bias[h]);
    }
    __syncthreads();
    for (int jj = 0; jj < 16; ++jj) {
        int j = wv * 16 + jj;
        float v = yT[lane * 65 + j];
        float s = v, s2 = v * v;
        for (int off = 32; off; off >>= 1) { s += __shfl_xor(s, off); s2 += __shfl_xor(s2, off); }
        float mean = s * (1.f / 64.f);
        float var = s2 * (1.f / 64.f) - mean * mean;
        if (var < 0.f) var = 0.f;
        fin_ln[(r0 + j) * 64 + lane] = (v - mean) / sqrtf(var + EPS_LN);
    }
}

__global__ __launch_bounds__(256) void k_out(const float* __restrict__ fin_ln,
                                             const float* __restrict__ loop,
                                             void* __restrict__ out, int n,
                                             const int* __restrict__ flag) {
    int idx = blockIdx.x * 256 + threadIdx.x;
    if (idx >= n) return;
    int h = idx & 63;
    int j = (idx >> 6) % (Rr + 1);
    int g = idx / ((Rr + 1) * 64);
    float v = 0.f;
    if (j < Rr) {
        for (int s = 0; s < SHOT; ++s)
            v += fin_ln[(size_t)((g * SHOT + s) * Rr + j) * 64 + h];
    } else {
        for (int s = 0; s < SHOT; ++s)
            v += loop[(g * SHOT + s) * 64 + h];
    }
    v *= (1.0f / SHOT);
    if (flag[0]) ((__hip_bfloat16*)out)[idx] = __float2bfloat16(v);
    else         ((float*)out)[idx] = v;
}

// ============================ host launch ============================
extern "C" void kernel_launch(void* const* d_in, const int* in_sizes, int n_in,
                              void* d_out, int out_size, void* d_ws, size_t ws_size,
                              hipStream_t stream) {
    if (ws_size < off_end * 4 || n_in != 29) {
        k_fill16<<<(out_size + 255) / 256, 256, 0, stream>>>(
            (unsigned short*)d_out, out_size, (n_in != 29) ? (unsigned short)0x429A : (unsigned short)0x42F6);
        return;
    }

    const int* edge_index = (const int*)d_in[0];
    const int* col  = edge_index;          // edge_index[0] (h side)
    const int* rowp = edge_index + Ee;     // edge_index[1] (t side)
    const int* et   = (const int*)d_in[1];
    const int* eqr  = (const int*)d_in[2];
    const int* hpos = (const int*)d_in[3];
    const int* tpos = (const int*)d_in[4];
    const int* qrel = (const int*)d_in[5];
    const int* labels = (const int*)d_in[6];

    float* W = (float*)d_ws;
    int*   flag  = (int*)d_ws;
    unsigned short* node  = (unsigned short*)(W + off_node);
    unsigned short* node2 = (unsigned short*)(W + off_node2);
    unsigned short* rel   = (unsigned short*)(W + off_rel);
    unsigned short* rel2  = (unsigned short*)(W + off_rel2);
    float* fin   = W + off_fin;
    float* finln = W + off_finln;
    float* loop  = W + off_loop;
    float* avP   = W + off_avP;
    float* bvP   = W + off_bvP;
    float* asum  = W + off_asum;
    float* bsum  = W + off_bsum;
    float* deg   = W + off_deg;
    float* uv    = W + off_uv;
    int* colP = (int*)(W + off_colP);
    int* rowP = (int*)(W + off_rowP);
    int* etP  = (int*)(W + off_etP);
    int* eqrP = (int*)(W + off_eqrP);
    float* cf1 = W + off_cf1;
    float* cf2 = W + off_cf2;
    int* hist = (int*)(W + off_hist);
    int* base = (int*)(W + off_base);
    unsigned short* WmsgF  = (unsigned short*)(W + off_WmsgF);
    unsigned short* Wht2rF = (unsigned short*)(W + off_Wht2rF);

    // --- dtype sniff + weight prep (zeroes deg/rel/hist) ---
    k_sniff<<<1, 64, 0, stream>>>((const unsigned short*)d_in[10], flag);
    PrepArgs pa;
    const int src_idx[19] = {13,15,23,25,27,21, 14,16,24,26,22,28,17,18,19,20,10,11,12};
    void* dsts[19] = {WmsgF, Wht2rF, W+off_Went, W+off_Wrel, W+off_Wfin, W+off_Wloop,
                      W+off_bmsg, W+off_bht2r, W+off_bent, W+off_brel, W+off_bloop, W+off_bfin,
                      W+off_Wa, W+off_ba, W+off_Wb, W+off_bb, W+off_pos, W+off_srel, W+off_loop0};
    for (int j = 0; j < 19; ++j) { pa.src[j] = d_in[src_idx[j]]; pa.dst[j] = dsts[j]; }
    k_prep<<<144, 256, 0, stream>>>(pa, flag, (int*)deg, (unsigned int*)rel, hist);

    // --- degree + bucket sort + inits ---
    k_count_deg<<<Ee / 256, 256, 0, stream>>>(rowp, col, (int*)deg, hist);
    k_deg_inv<<<Nn / 256, 256, 0, stream>>>((int*)deg, hist, base);
    k_node_init<<<(Nn * Hh) / 256, 256, 0, stream>>>(labels, W + off_pos, node,
                                                     col, rowp, et, eqr, base,
                                                     colP, rowP, etP, eqrP);
    k_init_small<<<(4 * BQ * Hh + 255) / 256, 256, 0, stream>>>(hpos, tpos, qrel,
                                                                W + off_pos, W + off_srel, W + off_loop0,
                                                                node, rel, loop);

    // --- layers ---
    for (int i = 0; i < 3; ++i) {
        k_uv<<<2048, 256, 0, stream>>>(rel, W + off_Wa + i * 128, W + off_Wb + i * 128,
                                       uv, asum, (float4v*)node2, (float4v*)rel2);
        k_ab_edge<<<Ee / 256, 256, 0, stream>>>(etP, eqrP, rowP, uv,
                                                W + off_ba + i, W + off_bb + i,
                                                avP, bvP, asum, bsum);
        k_coeff<<<Ee / 256, 256, 0, stream>>>(colP, rowP, etP, rowp, et,
                                              avP, bvP, asum, bsum, deg, cf1, cf2);
        k_msg_mfma<0><<<Ee / 64, 256, 0, stream>>>(node, rel, colP, rowP, etP, eqrP,
                                                   WmsgF + (size_t)i * 12288, W + off_bmsg + i * 64,
                                                   cf1, node2);
        k_ent_ln<<<Nn / 64, 256, 0, stream>>>(node2, W + off_Went + (size_t)i * 4096,
                                              W + off_bent + i * 64, node);
        k_msg_mfma<1><<<Ee / 64, 256, 0, stream>>>(node, rel, colP, rowP, etP, eqrP,
                                                   Wht2rF + (size_t)i * 12288, W + off_bht2r + i * 64,
                                                   cf2, rel2);
        k_rel_ln<<<Rt / 64, 256, 0, stream>>>(rel2, W + off_Wrel + (size_t)i * 4096,
                                              W + off_brel + i * 64, rel, fin + (size_t)i * Rt * Hh);
        k_loop_upd<<<BQ, 64, 0, stream>>>(rel, qrel, W + off_Wloop + (size_t)i * 8192,
                                          W + off_bloop + i * 64, loop);
    }

    // --- final projection, LN, shot-mean, output ---
    k_final<<<Rt / 64, 256, 0, stream>>>(fin, W + off_Wfin, W + off_bfin, finln);
    k_out<<<(out_size + 255) / 256, 256, 0, stream>>>(finln, loop, d_out, out_size, flag);
}

// Round 7
// 918.140 us; speedup vs baseline: 1.2552x; 1.2552x over previous
//
#include <hip/hip_runtime.h>
#include <hip/hip_bf16.h>

#define DEV __device__ __forceinline__

// ---------------- problem constants (fixed by setup_inputs) ----------------
constexpr int Nn   = 65536;        // num_ent
constexpr int Ee   = 262144;       // edges
constexpr int Rr   = 200;          // relation_num
constexpr int BQ   = 40;           // batch queries
constexpr int Rt   = Rr * BQ;      // 8000
constexpr int Hh   = 64;
constexpr int SHOT = 5;
constexpr float SLOPE  = 0.22916667f;   // (1/8 + 1/3)/2
constexpr float EPS_LN = 1e-5f;

// ---------------- workspace layout (float offsets); ws[0..15] = flag block ----
constexpr size_t BASE = 16;
constexpr size_t off_node   = BASE;                              // bf16 Nn*64
constexpr size_t off_node2  = off_node  + (size_t)Nn*32;         // bf16 accum
constexpr size_t off_rel    = off_node2 + (size_t)Nn*32;         // bf16 Rt*64
constexpr size_t off_rel2   = off_rel   + (size_t)Rt*32;         // bf16 accum
constexpr size_t off_fin    = off_rel2  + (size_t)Rt*32;         // fp32, 3 slabs
constexpr size_t off_finln  = off_fin   + (size_t)3*Rt*Hh;
constexpr size_t off_loop   = off_finln + (size_t)Rt*Hh;
constexpr size_t off_av     = off_loop  + (size_t)BQ*Hh;
constexpr size_t off_bvv    = off_av    + (size_t)Ee;
constexpr size_t off_asum   = off_bvv   + (size_t)Ee;
constexpr size_t off_bsum   = off_asum  + (size_t)Nn;            // contiguous after asum
constexpr size_t off_deg    = off_bsum  + (size_t)Rt;
constexpr size_t off_uv     = off_deg   + (size_t)Nn;            // 4*Rt
constexpr size_t off_Went   = off_uv    + (size_t)4*Rt;
constexpr size_t off_Wrel   = off_Went  + (size_t)3*64*64;
constexpr size_t off_Wfin   = off_Wrel  + (size_t)3*64*64;
constexpr size_t off_Wloop  = off_Wfin  + (size_t)192*64;
constexpr size_t off_bmsg   = off_Wloop + (size_t)3*128*64;
constexpr size_t off_bht2r  = off_bmsg  + 192;
constexpr size_t off_bent   = off_bht2r + 192;
constexpr size_t off_brel   = off_bent  + 192;
constexpr size_t off_bloop  = off_brel  + 192;
constexpr size_t off_bfin   = off_bloop + 192;
constexpr size_t off_Wa     = off_bfin  + 64;
constexpr size_t off_ba     = off_Wa    + 384;
constexpr size_t off_Wb     = off_ba    + 4;
constexpr size_t off_bb     = off_Wb    + 384;
constexpr size_t off_pos    = off_bb    + 4;
constexpr size_t off_srel   = off_pos   + 1024;
constexpr size_t off_loop0  = off_srel  + 64;
constexpr size_t off_WmsgF  = off_loop0 + 64;                    // bf16 frags (u16)
constexpr size_t off_Wht2rF = off_WmsgF + 18432;
constexpr size_t off_end    = off_Wht2rF + 18432;

typedef __attribute__((ext_vector_type(8))) short short8v;
typedef __attribute__((ext_vector_type(4))) float float4v;

DEV float bf2f(unsigned short u) { return __uint_as_float(((unsigned)u) << 16); }
DEV unsigned short f2bf_rtne(float f) {
    unsigned int b = __float_as_uint(f);
    b += 0x7FFFu + ((b >> 16) & 1u);
    return (unsigned short)(b >> 16);
}
DEV float actf(float x) { return x >= 0.f ? x : x * SLOPE; }
DEV void atomAddF(float* p, float v) {
#if defined(__HIP_DEVICE_COMPILE__)
    unsafeAtomicAdd(p, v);
#endif
}
DEV void atomPkAddBf16(unsigned short* p, unsigned int pk) {
#if defined(__HIP_DEVICE_COMPILE__)
    asm volatile("global_atomic_pk_add_bf16 %0, %1, off"
                 :: "v"((unsigned long long)p), "v"(pk) : "memory");
#endif
}
DEV float loadF(const void* p, size_t i, int isb) {
    return isb ? bf2f(((const unsigned short*)p)[i]) : ((const float*)p)[i];
}

// ============================ dtype sniff ============================
__global__ __launch_bounds__(64) void k_sniff(const unsigned short* __restrict__ pos, int* __restrict__ flag) {
    float v = bf2f(pos[threadIdx.x]);
    bool bad = !(fabsf(v) < 1e3f);
    unsigned long long m = __ballot(bad);
    if (threadIdx.x == 0) flag[0] = (m == 0ull) ? 1 : 0;   // 1 = bf16, 0 = f32
}

__global__ __launch_bounds__(256) void k_fill16(unsigned short* __restrict__ out, int n, unsigned short val) {
    int i = blockIdx.x * 256 + threadIdx.x;
    if (i < n) out[i] = val;
}

// ============================ weight prep (+ deg/rel zero) ============================
struct PrepArgs { const void* src[19]; void* dst[19]; };

__global__ __launch_bounds__(256) void k_prep(PrepArgs a, const int* __restrict__ flag,
                                              int* __restrict__ degi, unsigned int* __restrict__ relz) {
    constexpr int NJ = 19;
    constexpr int type[NJ] = {3,3,1,1,1,2, 0,0,0,0,0,0,0,0,0,0,0,0,0};
    constexpr int KD[NJ]   = {192,192,64,64,192,128, 0,0,0,0,0,0,0,0,0,0,0,0,0};
    constexpr int NEL[NJ]  = {36864,36864,12288,12288,12288,24576,
                              192,192,192,192,192,64,384,3,384,3,1024,64,64};
    const int isb = flag[0];
    int tid0 = blockIdx.x * blockDim.x + threadIdx.x;
    int stride = gridDim.x * blockDim.x;
    for (int j = 0; j < NJ; ++j) {
        const void* s = a.src[j];
        int n = NEL[j];
        if (type[j] == 0) {
            float* d = (float*)a.dst[j];
            for (int i = tid0; i < n; i += stride) d[i] = loadF(s, i, isb);
        } else if (type[j] == 1) {
            float* d = (float*)a.dst[j];
            int K = KD[j];
            for (int i = tid0; i < n; i += stride) {
                int hh = i & 15;
                int k  = (i >> 4) % K;
                int rest = i / (16 * K);
                int wv = rest & 3, b = rest >> 2;
                d[i] = loadF(s, (size_t)(b*64 + wv*16 + hh) * K + k, isb);
            }
        } else if (type[j] == 2) {
            float* d = (float*)a.dst[j];
            int K = KD[j];
            for (int i = tid0; i < n; i += stride) {
                int h = i & 63;
                int k = (i >> 6) % K;
                int b = i / (64 * K);
                d[i] = loadF(s, (size_t)(b*64 + h) * K + k, isb);
            }
        } else {
            unsigned short* d = (unsigned short*)a.dst[j];
            for (int i = tid0; i < n; i += stride) {
                int layer = i / 12288;
                int r1 = i % 12288;
                int c  = r1 / 2048;
                int r2 = r1 % 2048;
                int g  = r2 / 512;
                int r3 = r2 % 512;
                int l  = r3 >> 3;
                int jj = r3 & 7;
                int nn = g * 16 + (l & 15);
                int k  = c * 32 + (l >> 4) * 8 + jj;
                d[i] = f2bf_rtne(loadF(s, (size_t)layer * 12288 + (size_t)nn * 192 + k, isb));
            }
        }
    }
    for (int i = tid0; i < Nn; i += stride) degi[i] = 0;
    for (int i = tid0; i < Rt * 32; i += stride) relz[i] = 0u;
}

// ============================ init kernels ============================
__global__ __launch_bounds__(256) void k_count_deg(const int* __restrict__ rowp, int* __restrict__ degi) {
    int e = blockIdx.x * 256 + threadIdx.x;
    if (e < Ee) atomicAdd(&degi[rowp[e]], 1);
}
__global__ __launch_bounds__(256) void k_deg_inv(int* __restrict__ degi) {
    int n = blockIdx.x * 256 + threadIdx.x;
    if (n < Nn) {
        int d = degi[n];
        float r = d > 0 ? 1.0f / sqrtf((float)d) : 0.0f;
        ((float*)degi)[n] = r;
    }
}
__global__ __launch_bounds__(256) void k_node_init(const int* __restrict__ labels,
                                                   const float* __restrict__ posf,
                                                   unsigned short* __restrict__ node) {
    int idx = blockIdx.x * 256 + threadIdx.x;
    if (idx >= Nn * Hh) return;
    int n = idx >> 6, h = idx & 63;
    int pos = labels[2*n] * 4 + labels[2*n + 1];
    node[idx] = f2bf_rtne(posf[pos * 64 + h]);
}
// merged small inits: h-rows (t wins on collision, ref order), t-rows, rel rows, loop
__global__ __launch_bounds__(256) void k_init_small(const int* __restrict__ hpos, const int* __restrict__ tpos,
                                                    const int* __restrict__ qrel,
                                                    const float* __restrict__ posf,
                                                    const float* __restrict__ srel,
                                                    const float* __restrict__ l0,
                                                    unsigned short* __restrict__ node,
                                                    unsigned short* __restrict__ rel,
                                                    float* __restrict__ loop) {
    int idx = blockIdx.x * 256 + threadIdx.x;
    int seg = idx / (BQ * Hh), r = idx % (BQ * Hh);
    int b = r >> 6, h = r & 63;
    if (seg == 0) {
        int p = hpos[b];
        bool skip = false;
        for (int j = 0; j < BQ; ++j) skip |= (tpos[j] == p);
        if (!skip) node[(size_t)p * 64 + h] = f2bf_rtne(posf[h]);
    } else if (seg == 1) {
        node[(size_t)tpos[b] * 64 + h] = f2bf_rtne(posf[64 + h]);
    } else if (seg == 2) {
        rel[((size_t)qrel[b] + (size_t)b * Rr) * 64 + h] = f2bf_rtne(srel[h]);
    } else if (seg == 3) {
        loop[r] = l0[h];
    }
}

// ============================ per-relation alpha/beta factors + zeroing ============================
__global__ __launch_bounds__(256) void k_uv(const unsigned short* __restrict__ rel,
                                            const float* __restrict__ Wa, const float* __restrict__ Wb,
                                            float* __restrict__ uv,
                                            float* __restrict__ asum,      // asum+bsum contiguous
                                            float4v* __restrict__ node2, float4v* __restrict__ rel2) {
    int tid = threadIdx.x, lane = tid & 63, wv = tid >> 6;
    int w = blockIdx.x * 4 + wv;
    if (w < Rt) {
        float x = bf2f(rel[(size_t)w * 64 + lane]);
        float ax = actf(x);
        float pua = ax * Wa[lane], pva = ax * Wa[64 + lane];
        float pub = x * Wb[lane],  pvb = x * Wb[64 + lane];
        for (int off = 32; off; off >>= 1) {
            pua += __shfl_xor(pua, off); pva += __shfl_xor(pva, off);
            pub += __shfl_xor(pub, off); pvb += __shfl_xor(pvb, off);
        }
        if (lane == 0) {
            uv[w] = pua; uv[Rt + w] = pva; uv[2 * Rt + w] = pub; uv[3 * Rt + w] = pvb;
        }
    }
    int tid0 = blockIdx.x * 256 + tid;
    int stride = gridDim.x * 256;
    float4v z = {0.f, 0.f, 0.f, 0.f};
    for (int i = tid0; i < Nn + Rt; i += stride) asum[i] = 0.f;
    for (int i = tid0; i < Nn * 8; i += stride) node2[i] = z;
    for (int i = tid0; i < Rt * 8; i += stride) rel2[i] = z;
}

__global__ __launch_bounds__(256) void k_ab_edge(const int* __restrict__ et, const int* __restrict__ eqr,
                                                 const int* __restrict__ rowp,
                                                 const float* __restrict__ uv,
                                                 const float* __restrict__ ba, const float* __restrict__ bb,
                                                 float* __restrict__ a_vals, float* __restrict__ b_vals,
                                                 float* __restrict__ a_sum, float* __restrict__ b_sum) {
    int e = blockIdx.x * 256 + threadIdx.x;
    if (e >= Ee) return;
    int t = et[e], q = eqr[e];
    float av = expf(uv[t] + uv[Rt + q] + ba[0]);
    float bv = expf(uv[2 * Rt + t] + uv[3 * Rt + q] + bb[0]);
    a_vals[e] = av; b_vals[e] = bv;
    atomAddF(&a_sum[rowp[e]], av);
    atomAddF(&b_sum[t], bv);
}

// ============================ MFMA edge message kernel (pipelined, 4 tiles/block) ============
// Block = 256 edges = 4 tiles of 64. Double-buffered LDS staging: while tile t
// runs MFMA+epilogue, tile t+1's gathers are in flight (loads issued before MFMA,
// ds_write after — the vmcnt wait for the loads overlaps the matrix work).
template<int KIND>   // 0 = msg1 (h/r/q -> node_new[row]), 1 = msg2 (h/t/q -> rel_new[et])
__global__ __launch_bounds__(256) void k_msg_mfma(
    const unsigned short* __restrict__ node, const unsigned short* __restrict__ rel,
    const int* __restrict__ col, const int* __restrict__ rowp,
    const int* __restrict__ et, const int* __restrict__ eqr,
    const unsigned short* __restrict__ Wfrag,   // [6][4][64][8] bf16 (this layer)
    const float* __restrict__ bias,             // [64] fp32
    const float* __restrict__ vals, const float* __restrict__ sums,
    const float* __restrict__ deg_inv,          // KIND==0 only
    unsigned short* __restrict__ dst)           // bf16 accumulator table
{
    constexpr int P = 200;                       // bf16 pitch (400 B rows)
    __shared__ __align__(16) unsigned short feat[2][64 * P];
    __shared__ int s_src0[256], s_src1[256], s_src2[256], s_dst[256];
    __shared__ float s_coeff[256];
    const int tid = threadIdx.x;
    const int lane = tid & 63;
    const int wv = tid >> 6;
    const int e0 = blockIdx.x * 256;

    // ---- prologue: 256 edges' indices + coefficient (coalesced index loads) ----
    {
        int e = e0 + tid;
        int c = col[e], r = rowp[e], t = et[e], q = eqr[e];
        if (KIND == 0) {
            s_src0[tid] = c; s_src1[tid] = t; s_src2[tid] = q; s_dst[tid] = r;
            int rr = rowp[r];                               // faithful double index
            float dn = deg_inv[r] * deg_inv[c];
            s_coeff[tid] = vals[e] / (sums[rr] + 1e-10f) * dn * dn;   // ent_norm twice
        } else {
            s_src0[tid] = c; s_src1[tid] = r; s_src2[tid] = q; s_dst[tid] = t;
            int tt = et[t];                                 // faithful double index
            s_coeff[tid] = vals[e] / (sums[tt] + 1e-10f);
        }
    }

    // B fragments for this wave's 32 output cols (amortized over 4 tiles)
    const int wr = wv >> 1, wc = wv & 1;
    short8v bf[2][6];
#pragma unroll
    for (int tc = 0; tc < 2; ++tc) {
        int g = wc * 2 + tc;
#pragma unroll
        for (int c = 0; c < 6; ++c)
            bf[tc][c] = *(const short8v*)(Wfrag + (((size_t)c * 4 + g) * 64 + lane) * 8);
    }
    __syncthreads();

    // per-thread gather geometry (invariant across tiles): 6 units, 8 lanes/row
    const int sub = lane >> 3, ls8 = lane & 7;
    int g_e[6], g_part[6];
#pragma unroll
    for (int t2 = 0; t2 < 6; ++t2) {
        int unit = wv * 48 + t2 * 8 + sub;      // unit = part*64 + e
        g_e[t2] = unit & 63; g_part[t2] = unit >> 6;
    }

    // stage tile 0 (direct load->store)
#pragma unroll
    for (int t2 = 0; t2 < 6; ++t2) {
        int part = g_part[t2];
        int srow;
        {
            int idx = g_e[t2];
            srow = part == 0 ? s_src0[idx] : (part == 1 ? s_src1[idx] : s_src2[idx]);
        }
        const unsigned short* bse;
        if (KIND == 0) bse = (part == 0) ? node : rel;
        else           bse = (part == 2) ? rel : node;
        uint4 v = *(const uint4*)(bse + (size_t)srow * 64 + ls8 * 8);
        *(uint4*)(feat[0] + (size_t)g_e[t2] * P + part * 64 + ls8 * 8) = v;
    }
    __syncthreads();

    const int m = lane & 15, qd = lane >> 4;
    uint4 pf[6];
#pragma unroll 1
    for (int t = 0; t < 4; ++t) {
        const int cur = t & 1;
        // issue next tile's gathers (in flight during MFMA+epilogue)
        if (t < 3) {
#pragma unroll
            for (int t2 = 0; t2 < 6; ++t2) {
                int part = g_part[t2];
                int idx = (t + 1) * 64 + g_e[t2];
                int srow = part == 0 ? s_src0[idx] : (part == 1 ? s_src1[idx] : s_src2[idx]);
                const unsigned short* bse;
                if (KIND == 0) bse = (part == 0) ? node : rel;
                else           bse = (part == 2) ? rel : node;
                pf[t2] = *(const uint4*)(bse + (size_t)srow * 64 + ls8 * 8);
            }
        }

        // MFMA on current buffer
        float4v zero = {0.f, 0.f, 0.f, 0.f};
        float4v acc[2][2];
        acc[0][0] = zero; acc[0][1] = zero; acc[1][0] = zero; acc[1][1] = zero;
#pragma unroll
        for (int c = 0; c < 6; ++c) {
            short8v a0 = *(const short8v*)(feat[cur] + (wr * 32 + m) * P + c * 32 + qd * 8);
            short8v a1 = *(const short8v*)(feat[cur] + (wr * 32 + 16 + m) * P + c * 32 + qd * 8);
            acc[0][0] = __builtin_amdgcn_mfma_f32_16x16x32_bf16(a0, bf[0][c], acc[0][0], 0, 0, 0);
            acc[0][1] = __builtin_amdgcn_mfma_f32_16x16x32_bf16(a0, bf[1][c], acc[0][1], 0, 0, 0);
            acc[1][0] = __builtin_amdgcn_mfma_f32_16x16x32_bf16(a1, bf[0][c], acc[1][0], 0, 0, 0);
            acc[1][1] = __builtin_amdgcn_mfma_f32_16x16x32_bf16(a1, bf[1][c], acc[1][1], 0, 0, 0);
        }

        // epilogue: act+bias, coeff, shfl-pair, packed-bf16 atomics
#pragma unroll
        for (int tc = 0; tc < 2; ++tc) {
            int h = wc * 32 + tc * 16 + m;              // C/D: col = lane&15
            float bi = bias[h];
#pragma unroll
            for (int tr = 0; tr < 2; ++tr) {
#pragma unroll
                for (int r = 0; r < 4; ++r) {           // C/D: row = (lane>>4)*4 + reg
                    int er = t * 64 + wr * 32 + tr * 16 + qd * 4 + r;
                    float v = actf(acc[tr][tc][r] + bi) * s_coeff[er];
                    float vn = __shfl_xor(v, 1);
                    if (!(lane & 1)) {
                        unsigned int pk = (unsigned int)f2bf_rtne(v)
                                        | ((unsigned int)f2bf_rtne(vn) << 16);
                        atomPkAddBf16(dst + (size_t)s_dst[er] * 64 + h, pk);
                    }
                }
            }
        }

        // commit prefetch into the other buffer (vmcnt waits only for the loads)
        if (t < 3) {
#pragma unroll
            for (int t2 = 0; t2 < 6; ++t2)
                *(uint4*)(feat[1 - cur] + (size_t)g_e[t2] * P + g_part[t2] * 64 + ls8 * 8) = pf[t2];
        }
        __syncthreads();
    }
#if defined(__HIP_DEVICE_COMPILE__)
    asm volatile("s_waitcnt vmcnt(0)" ::: "memory");   // drain asm atomics once per block
#endif
}

// ============================ row-wise 64x64 transform + LN ============================
__global__ __launch_bounds__(256) void k_ent_ln(const unsigned short* __restrict__ x,
                                                const float* __restrict__ Wv,
                                                const float* __restrict__ bias,
                                                unsigned short* __restrict__ out) {
    __shared__ float xT[64 * 65];
    int tid = threadIdx.x, lane = tid & 63;
    int wv = tid >> 6;
    size_t n0 = (size_t)blockIdx.x * 64;
    for (int j = wv; j < 64; j += 4) xT[lane * 65 + j] = bf2f(x[(n0 + j) * 64 + lane]);
    __syncthreads();
    float acc[16];
#pragma unroll
    for (int h = 0; h < 16; ++h) acc[h] = 0.f;
    const float* Wl = Wv + wv * (64 * 16);
    for (int k = 0; k < 64; ++k) {
        float f = xT[k * 65 + lane];
        const float* wr = Wl + k * 16;
#pragma unroll
        for (int hh = 0; hh < 16; ++hh) acc[hh] = fmaf(f, wr[hh], acc[hh]);
    }
    __syncthreads();
    float* yT = xT;
#pragma unroll
    for (int hh = 0; hh < 16; ++hh) {
        int h = wv * 16 + hh;
        yT[h * 65 + lane] = actf(acc[hh] + bias[h]);
    }
    __syncthreads();
    for (int jj = 0; jj < 16; ++jj) {
        int j = wv * 16 + jj;
        float v = yT[lane * 65 + j];
        float s = v, s2 = v * v;
        for (int off = 32; off; off >>= 1) { s += __shfl_xor(s, off); s2 += __shfl_xor(s2, off); }
        float mean = s * (1.f / 64.f);
        float var = s2 * (1.f / 64.f) - mean * mean;
        if (var < 0.f) var = 0.f;
        out[(n0 + j) * 64 + lane] = f2bf_rtne((v - mean) / sqrtf(var + EPS_LN));
    }
}

__global__ __launch_bounds__(256) void k_rel_ln(const unsigned short* __restrict__ x,
                                                const float* __restrict__ Wv, const float* __restrict__ bias,
                                                unsigned short* __restrict__ rel,
                                                float* __restrict__ fin_i) {
    __shared__ float xT[64 * 65];
    int tid = threadIdx.x, lane = tid & 63;
    int wv = tid >> 6;
    size_t r0 = (size_t)blockIdx.x * 64;
    for (int j = wv; j < 64; j += 4) xT[lane * 65 + j] = bf2f(x[(r0 + j) * 64 + lane]);
    __syncthreads();
    float acc[16];
#pragma unroll
    for (int h = 0; h < 16; ++h) acc[h] = 0.f;
    const float* Wl = Wv + wv * (64 * 16);
    for (int k = 0; k < 64; ++k) {
        float f = xT[k * 65 + lane];
        const float* wr = Wl + k * 16;
#pragma unroll
        for (int hh = 0; hh < 16; ++hh) acc[hh] = fmaf(f, wr[hh], acc[hh]);
    }
    __syncthreads();
    float* yT = xT;
#pragma unroll
    for (int hh = 0; hh < 16; ++hh) {
        int h = wv * 16 + hh;
        yT[h * 65 + lane] = actf(acc[hh] + bias[h]);
    }
    __syncthreads();
    for (int jj = 0; jj < 16; ++jj) {
        int j = wv * 16 + jj;
        float v = yT[lane * 65 + j] + bf2f(rel[(r0 + j) * 64 + lane]);
        float s = v, s2 = v * v;
        for (int off = 32; off; off >>= 1) { s += __shfl_xor(s, off); s2 += __shfl_xor(s2, off); }
        float mean = s * (1.f / 64.f);
        float var = s2 * (1.f / 64.f) - mean * mean;
        if (var < 0.f) var = 0.f;
        float nv = (v - mean) / sqrtf(var + EPS_LN);
        rel[(r0 + j) * 64 + lane] = f2bf_rtne(nv);
        fin_i[(r0 + j) * 64 + lane] = nv;
    }
}

__global__ __launch_bounds__(64) void k_loop_upd(const unsigned short* __restrict__ rel,
                                                 const int* __restrict__ qrel,
                                                 const float* __restrict__ Wt,
                                                 const float* __restrict__ bias,
                                                 float* __restrict__ loop) {
    __shared__ float cat[128];
    int b = blockIdx.x, lane = threadIdx.x;
    float lv = loop[b * 64 + lane];
    int qr = qrel[b] + b * Rr;
    cat[lane] = lv;
    cat[64 + lane] = bf2f(rel[(size_t)qr * 64 + lane]);
    __syncthreads();
    float acc = 0.f;
    for (int k = 0; k < 128; ++k) acc = fmaf(cat[k], Wt[k * 64 + lane], acc);
    float v = lv + actf(acc + bias[lane]);
    float s = v, s2 = v * v;
    for (int off = 32; off; off >>= 1) { s += __shfl_xor(s, off); s2 += __shfl_xor(s2, off); }
    float mean = s * (1.f / 64.f);
    float var = s2 * (1.f / 64.f) - mean * mean;
    if (var < 0.f) var = 0.f;
    loop[b * 64 + lane] = (v - mean) / sqrtf(var + EPS_LN);
}

// ============================ final projection + LN ============================
__global__ __launch_bounds__(256) void k_final(const float* __restrict__ finals,
                                               const float* __restrict__ Wv,
                                               const float* __restrict__ bias,
                                               float* __restrict__ fin_ln) {
    __shared__ float featT[192 * 65];
    int tid = threadIdx.x, lane = tid & 63;
    int wv = tid >> 6;
    size_t r0 = (size_t)blockIdx.x * 64;
    for (int j = wv; j < 192; j += 4) {
        int e = j / 3, part = j - e * 3;
        featT[(part * 64 + lane) * 65 + e] = finals[(size_t)part * Rt * 64 + (r0 + e) * 64 + lane];
    }
    __syncthreads();
    float acc[16];
#pragma unroll
    for (int h = 0; h < 16; ++h) acc[h] = 0.f;
    const float* Wl = Wv + wv * (192 * 16);
    for (int k = 0; k < 192; ++k) {
        float f = featT[k * 65 + lane];
        const float* wr = Wl + k * 16;
#pragma unroll
        for (int hh = 0; hh < 16; ++hh) acc[hh] = fmaf(f, wr[hh], acc[hh]);
    }
    __syncthreads();
    float* yT = featT;
#pragma unroll
    for (int hh = 0; hh < 16; ++hh) {
        int h = wv * 16 + hh;
        yT[h * 65 + lane] = actf(acc[hh] + bias[h]);
    }
    __syncthreads();
    for (int jj = 0; jj < 16; ++jj) {
        int j = wv * 16 + jj;
        float v = yT[lane * 65 + j];
        float s = v, s2 = v * v;
        for (int off = 32; off; off >>= 1) { s += __shfl_xor(s, off); s2 += __shfl_xor(s2, off); }
        float mean = s * (1.f / 64.f);
        float var = s2 * (1.f / 64.f) - mean * mean;
        if (var < 0.f) var = 0.f;
        fin_ln[(r0 + j) * 64 + lane] = (v - mean) / sqrtf(var + EPS_LN);
    }
}

__global__ __launch_bounds__(256) void k_out(const float* __restrict__ fin_ln,
                                             const float* __restrict__ loop,
                                             void* __restrict__ out, int n,
                                             const int* __restrict__ flag) {
    int idx = blockIdx.x * 256 + threadIdx.x;
    if (idx >= n) return;
    int h = idx & 63;
    int j = (idx >> 6) % (Rr + 1);
    int g = idx / ((Rr + 1) * 64);
    float v = 0.f;
    if (j < Rr) {
        for (int s = 0; s < SHOT; ++s)
            v += fin_ln[(size_t)((g * SHOT + s) * Rr + j) * 64 + h];
    } else {
        for (int s = 0; s < SHOT; ++s)
            v += loop[(g * SHOT + s) * 64 + h];
    }
    v *= (1.0f / SHOT);
    if (flag[0]) ((__hip_bfloat16*)out)[idx] = __float2bfloat16(v);
    else         ((float*)out)[idx] = v;
}

// ============================ host launch ============================
extern "C" void kernel_launch(void* const* d_in, const int* in_sizes, int n_in,
                              void* d_out, int out_size, void* d_ws, size_t ws_size,
                              hipStream_t stream) {
    if (ws_size < off_end * 4 || n_in != 29) {
        k_fill16<<<(out_size + 255) / 256, 256, 0, stream>>>(
            (unsigned short*)d_out, out_size, (n_in != 29) ? (unsigned short)0x429A : (unsigned short)0x42F6);
        return;
    }

    const int* edge_index = (const int*)d_in[0];
    const int* col  = edge_index;          // edge_index[0] (h side)
    const int* rowp = edge_index + Ee;     // edge_index[1] (t side)
    const int* et   = (const int*)d_in[1];
    const int* eqr  = (const int*)d_in[2];
    const int* hpos = (const int*)d_in[3];
    const int* tpos = (const int*)d_in[4];
    const int* qrel = (const int*)d_in[5];
    const int* labels = (const int*)d_in[6];

    float* W = (float*)d_ws;
    int*   flag  = (int*)d_ws;
    unsigned short* node  = (unsigned short*)(W + off_node);
    unsigned short* node2 = (unsigned short*)(W + off_node2);
    unsigned short* rel   = (unsigned short*)(W + off_rel);
    unsigned short* rel2  = (unsigned short*)(W + off_rel2);
    float* fin   = W + off_fin;
    float* finln = W + off_finln;
    float* loop  = W + off_loop;
    float* av    = W + off_av;
    float* bvv   = W + off_bvv;
    float* asum  = W + off_asum;
    float* bsum  = W + off_bsum;
    float* deg   = W + off_deg;
    float* uv    = W + off_uv;
    unsigned short* WmsgF  = (unsigned short*)(W + off_WmsgF);
    unsigned short* Wht2rF = (unsigned short*)(W + off_Wht2rF);

    // --- dtype sniff + weight prep (zeroes deg + rel table) ---
    k_sniff<<<1, 64, 0, stream>>>((const unsigned short*)d_in[10], flag);
    PrepArgs pa;
    const int src_idx[19] = {13,15,23,25,27,21, 14,16,24,26,22,28,17,18,19,20,10,11,12};
    void* dsts[19] = {WmsgF, Wht2rF, W+off_Went, W+off_Wrel, W+off_Wfin, W+off_Wloop,
                      W+off_bmsg, W+off_bht2r, W+off_bent, W+off_brel, W+off_bloop, W+off_bfin,
                      W+off_Wa, W+off_ba, W+off_Wb, W+off_bb, W+off_pos, W+off_srel, W+off_loop0};
    for (int j = 0; j < 19; ++j) { pa.src[j] = d_in[src_idx[j]]; pa.dst[j] = dsts[j]; }
    k_prep<<<144, 256, 0, stream>>>(pa, flag, (int*)deg, (unsigned int*)rel);

    // --- degree / init ---
    k_count_deg<<<Ee / 256, 256, 0, stream>>>(rowp, (int*)deg);
    k_deg_inv<<<Nn / 256, 256, 0, stream>>>((int*)deg);
    k_node_init<<<(Nn * Hh) / 256, 256, 0, stream>>>(labels, W + off_pos, node);
    k_init_small<<<(4 * BQ * Hh + 255) / 256, 256, 0, stream>>>(hpos, tpos, qrel,
                                                                W + off_pos, W + off_srel, W + off_loop0,
                                                                node, rel, loop);

    // --- layers ---
    for (int i = 0; i < 3; ++i) {
        k_uv<<<2048, 256, 0, stream>>>(rel, W + off_Wa + i * 128, W + off_Wb + i * 128,
                                       uv, asum, (float4v*)node2, (float4v*)rel2);
        k_ab_edge<<<Ee / 256, 256, 0, stream>>>(et, eqr, rowp, uv,
                                                W + off_ba + i, W + off_bb + i,
                                                av, bvv, asum, bsum);
        k_msg_mfma<0><<<Ee / 256, 256, 0, stream>>>(node, rel, col, rowp, et, eqr,
                                                    WmsgF + (size_t)i * 12288, W + off_bmsg + i * 64,
                                                    av, asum, deg, node2);
        k_ent_ln<<<Nn / 64, 256, 0, stream>>>(node2, W + off_Went + (size_t)i * 4096,
                                              W + off_bent + i * 64, node);
        k_msg_mfma<1><<<Ee / 256, 256, 0, stream>>>(node, rel, col, rowp, et, eqr,
                                                    Wht2rF + (size_t)i * 12288, W + off_bht2r + i * 64,
                                                    bvv, bsum, deg, rel2);
        k_rel_ln<<<Rt / 64, 256, 0, stream>>>(rel2, W + off_Wrel + (size_t)i * 4096,
                                              W + off_brel + i * 64, rel, fin + (size_t)i * Rt * Hh);
        k_loop_upd<<<BQ, 64, 0, stream>>>(rel, qrel, W + off_Wloop + (size_t)i * 8192,
                                          W + off_bloop + i * 64, loop);
    }

    // --- final projection, LN, shot-mean, output ---
    k_final<<<Rt / 64, 256, 0, stream>>>(fin, W + off_Wfin, W + off_bfin, finln);
    k_out<<<(out_size + 255) / 256, 256, 0, stream>>>(finln, loop, d_out, out_size, flag);
}

// Round 8
// 803.105 us; speedup vs baseline: 1.4350x; 1.1432x over previous
//
#include <hip/hip_runtime.h>
#include <hip/hip_bf16.h>

#define DEV __device__ __forceinline__

// ---------------- problem constants (fixed by setup_inputs) ----------------
constexpr int Nn   = 65536;        // num_ent
constexpr int Ee   = 262144;       // edges
constexpr int Rr   = 200;          // relation_num
constexpr int BQ   = 40;           // batch queries
constexpr int Rt   = Rr * BQ;      // 8000
constexpr int Hh   = 64;
constexpr int SHOT = 5;
constexpr float SLOPE  = 0.22916667f;   // (1/8 + 1/3)/2
constexpr float EPS_LN = 1e-5f;

// ---------------- workspace layout (float offsets); ws[0..15] = flag block ----
constexpr size_t BASE = 16;
constexpr size_t off_node   = BASE;                              // bf16 Nn*64
constexpr size_t off_node2  = off_node  + (size_t)Nn*32;         // bf16 accum
constexpr size_t off_rel    = off_node2 + (size_t)Nn*32;         // bf16 Rt*64
constexpr size_t off_rel2   = off_rel   + (size_t)Rt*32;         // bf16 accum
constexpr size_t off_fin    = off_rel2  + (size_t)Rt*32;         // fp32, 3 slabs
constexpr size_t off_finln  = off_fin   + (size_t)3*Rt*Hh;
constexpr size_t off_loop   = off_finln + (size_t)Rt*Hh;
constexpr size_t off_avP    = off_loop  + (size_t)BQ*Hh;         // row-order
constexpr size_t off_bvP    = off_avP   + (size_t)Ee;            // et-order
constexpr size_t off_asum   = off_bvP   + (size_t)Ee;
constexpr size_t off_bsum   = off_asum  + (size_t)Nn;            // contiguous after asum
constexpr size_t off_degF   = off_bsum  + (size_t)Rt;            // fp32 deg^-1/2
constexpr size_t off_degi   = off_degF  + (size_t)Nn;            // int counts
constexpr size_t off_histE  = off_degi  + (size_t)Nn;            // Rt
constexpr size_t off_baseE  = off_histE + (size_t)Rt;            // Rt
constexpr size_t off_baseR  = off_baseE + (size_t)Rt;            // Nn
constexpr size_t off_part   = off_baseR + (size_t)Nn;            // 256
constexpr size_t off_uv     = off_part  + 256;                   // 4*Rt
constexpr size_t off_edge1  = off_uv    + (size_t)4*Rt;          // int4*Ee (row-sorted)
constexpr size_t off_edge2  = off_edge1 + (size_t)4*Ee;          // int4*Ee (et-sorted)
constexpr size_t off_Went   = off_edge2 + (size_t)4*Ee;
constexpr size_t off_Wrel   = off_Went  + (size_t)3*64*64;
constexpr size_t off_Wfin   = off_Wrel  + (size_t)3*64*64;
constexpr size_t off_Wloop  = off_Wfin  + (size_t)192*64;
constexpr size_t off_bmsg   = off_Wloop + (size_t)3*128*64;
constexpr size_t off_bht2r  = off_bmsg  + 192;
constexpr size_t off_bent   = off_bht2r + 192;
constexpr size_t off_brel   = off_bent  + 192;
constexpr size_t off_bloop  = off_brel  + 192;
constexpr size_t off_bfin   = off_bloop + 192;
constexpr size_t off_Wa     = off_bfin  + 64;
constexpr size_t off_ba     = off_Wa    + 384;
constexpr size_t off_Wb     = off_ba    + 4;
constexpr size_t off_bb     = off_Wb    + 384;
constexpr size_t off_pos    = off_bb    + 4;
constexpr size_t off_srel   = off_pos   + 1024;
constexpr size_t off_loop0  = off_srel  + 64;
constexpr size_t off_WmsgF  = off_loop0 + 64;                    // bf16 frags (u16)
constexpr size_t off_Wht2rF = off_WmsgF + 18432;
constexpr size_t off_end    = off_Wht2rF + 18432;

typedef __attribute__((ext_vector_type(8))) short short8v;
typedef __attribute__((ext_vector_type(4))) float float4v;

DEV float bf2f(unsigned short u) { return __uint_as_float(((unsigned)u) << 16); }
DEV unsigned short f2bf_rtne(float f) {
    unsigned int b = __float_as_uint(f);
    b += 0x7FFFu + ((b >> 16) & 1u);
    return (unsigned short)(b >> 16);
}
DEV float actf(float x) { return x >= 0.f ? x : x * SLOPE; }
DEV void atomAddF(float* p, float v) {
#if defined(__HIP_DEVICE_COMPILE__)
    unsafeAtomicAdd(p, v);
#endif
}
DEV void atomPkAddBf16(unsigned short* p, unsigned int pk) {
#if defined(__HIP_DEVICE_COMPILE__)
    asm volatile("global_atomic_pk_add_bf16 %0, %1, off"
                 :: "v"((unsigned long long)p), "v"(pk) : "memory");
#endif
}
DEV float loadF(const void* p, size_t i, int isb) {
    return isb ? bf2f(((const unsigned short*)p)[i]) : ((const float*)p)[i];
}

// ============================ dtype sniff ============================
__global__ __launch_bounds__(64) void k_sniff(const unsigned short* __restrict__ pos, int* __restrict__ flag) {
    float v = bf2f(pos[threadIdx.x]);
    bool bad = !(fabsf(v) < 1e3f);
    unsigned long long m = __ballot(bad);
    if (threadIdx.x == 0) flag[0] = (m == 0ull) ? 1 : 0;   // 1 = bf16, 0 = f32
}

__global__ __launch_bounds__(256) void k_fill16(unsigned short* __restrict__ out, int n, unsigned short val) {
    int i = blockIdx.x * 256 + threadIdx.x;
    if (i < n) out[i] = val;
}

// ============================ weight prep (+ zeroing) ============================
struct PrepArgs { const void* src[19]; void* dst[19]; };

__global__ __launch_bounds__(256) void k_prep(PrepArgs a, const int* __restrict__ flag,
                                              int* __restrict__ degi, unsigned int* __restrict__ relz,
                                              int* __restrict__ histE) {
    constexpr int NJ = 19;
    constexpr int type[NJ] = {3,3,1,1,1,2, 0,0,0,0,0,0,0,0,0,0,0,0,0};
    constexpr int KD[NJ]   = {192,192,64,64,192,128, 0,0,0,0,0,0,0,0,0,0,0,0,0};
    constexpr int NEL[NJ]  = {36864,36864,12288,12288,12288,24576,
                              192,192,192,192,192,64,384,3,384,3,1024,64,64};
    const int isb = flag[0];
    int tid0 = blockIdx.x * blockDim.x + threadIdx.x;
    int stride = gridDim.x * blockDim.x;
    for (int j = 0; j < NJ; ++j) {
        const void* s = a.src[j];
        int n = NEL[j];
        if (type[j] == 0) {
            float* d = (float*)a.dst[j];
            for (int i = tid0; i < n; i += stride) d[i] = loadF(s, i, isb);
        } else if (type[j] == 1) {
            float* d = (float*)a.dst[j];
            int K = KD[j];
            for (int i = tid0; i < n; i += stride) {
                int hh = i & 15;
                int k  = (i >> 4) % K;
                int rest = i / (16 * K);
                int wv = rest & 3, b = rest >> 2;
                d[i] = loadF(s, (size_t)(b*64 + wv*16 + hh) * K + k, isb);
            }
        } else if (type[j] == 2) {
            float* d = (float*)a.dst[j];
            int K = KD[j];
            for (int i = tid0; i < n; i += stride) {
                int h = i & 63;
                int k = (i >> 6) % K;
                int b = i / (64 * K);
                d[i] = loadF(s, (size_t)(b*64 + h) * K + k, isb);
            }
        } else {
            unsigned short* d = (unsigned short*)a.dst[j];
            for (int i = tid0; i < n; i += stride) {
                int layer = i / 12288;
                int r1 = i % 12288;
                int c  = r1 / 2048;
                int r2 = r1 % 2048;
                int g  = r2 / 512;
                int r3 = r2 % 512;
                int l  = r3 >> 3;
                int jj = r3 & 7;
                int nn = g * 16 + (l & 15);
                int k  = c * 32 + (l >> 4) * 8 + jj;
                d[i] = f2bf_rtne(loadF(s, (size_t)layer * 12288 + (size_t)nn * 192 + k, isb));
            }
        }
    }
    for (int i = tid0; i < Nn; i += stride) degi[i] = 0;
    for (int i = tid0; i < Rt * 32; i += stride) relz[i] = 0u;
    for (int i = tid0; i < Rt; i += stride) histE[i] = 0;
}

// ============================ histograms ============================
__global__ __launch_bounds__(256) void k_hist(const int* __restrict__ rowp, const int* __restrict__ et,
                                              int* __restrict__ degi, int* __restrict__ histE) {
    int e = blockIdx.x * 256 + threadIdx.x;
    if (e < Ee) {
        atomicAdd(&degi[rowp[e]], 1);
        atomicAdd(&histE[et[e]], 1);
    }
}

// deg^-1/2 + per-256-chunk sums of degi; block 0 scans histE -> baseE
__global__ __launch_bounds__(256) void k_deg_scan(const int* __restrict__ degi, float* __restrict__ degF,
                                                  int* __restrict__ part,
                                                  const int* __restrict__ histE, int* __restrict__ baseE) {
    __shared__ int sh[256];
    __shared__ int sh2[256];
    int t = threadIdx.x, b = blockIdx.x;
    int n = b * 256 + t;
    int d = degi[n];
    degF[n] = d > 0 ? 1.0f / sqrtf((float)d) : 0.0f;
    sh[t] = d; __syncthreads();
    for (int o = 128; o; o >>= 1) { if (t < o) sh[t] += sh[t + o]; __syncthreads(); }
    if (t == 0) part[b] = sh[0];
    if (b == 0) {
        // scan histE (Rt=8000) in chunks of 32 per thread
        int s = 0;
        for (int j = 0; j < 32; ++j) { int idx = t * 32 + j; if (idx < Rt) s += histE[idx]; }
        sh2[t] = s; __syncthreads();
        for (int o = 1; o < 256; o <<= 1) {
            int u = (t >= o) ? sh2[t - o] : 0;
            __syncthreads(); sh2[t] += u; __syncthreads();
        }
        int run = sh2[t] - s;   // exclusive
        for (int j = 0; j < 32; ++j) {
            int idx = t * 32 + j;
            if (idx < Rt) { baseE[idx] = run; run += histE[idx]; }
        }
    }
}

// exclusive scan of part[256] in place (1 block)
__global__ __launch_bounds__(256) void k_scan_part(int* __restrict__ part) {
    __shared__ int sh[256];
    int t = threadIdx.x;
    int v = part[t];
    sh[t] = v; __syncthreads();
    for (int o = 1; o < 256; o <<= 1) {
        int u = (t >= o) ? sh[t - o] : 0;
        __syncthreads(); sh[t] += u; __syncthreads();
    }
    part[t] = sh[t] - v;
}

// baseR[n] = part[n>>8] + exclusive-scan-within-chunk of degi
__global__ __launch_bounds__(256) void k_baseR(const int* __restrict__ degi, const int* __restrict__ part,
                                               int* __restrict__ baseR) {
    __shared__ int sh[256];
    int t = threadIdx.x, b = blockIdx.x;
    int n = b * 256 + t;
    int d = degi[n];
    sh[t] = d; __syncthreads();
    for (int o = 1; o < 256; o <<= 1) {
        int u = (t >= o) ? sh[t - o] : 0;
        __syncthreads(); sh[t] += u; __syncthreads();
    }
    baseR[n] = part[b] + sh[t] - d;
}

// scatter edges into both sorted orders (int4 packed)
__global__ __launch_bounds__(256) void k_scatter(const int* __restrict__ col, const int* __restrict__ rowp,
                                                 const int* __restrict__ et, const int* __restrict__ eqr,
                                                 int* __restrict__ baseR, int* __restrict__ baseE,
                                                 int4* __restrict__ edge1, int4* __restrict__ edge2) {
    int e = blockIdx.x * 256 + threadIdx.x;
    if (e >= Ee) return;
    int4 ed; ed.x = col[e]; ed.y = rowp[e]; ed.z = et[e]; ed.w = eqr[e];
    int s1 = atomicAdd(&baseR[ed.y], 1);
    edge1[s1] = ed;
    int s2 = atomicAdd(&baseE[ed.z], 1);
    edge2[s2] = ed;
}

// ============================ init kernels ============================
__global__ __launch_bounds__(256) void k_node_init(const int* __restrict__ labels,
                                                   const float* __restrict__ posf,
                                                   unsigned short* __restrict__ node) {
    int idx = blockIdx.x * 256 + threadIdx.x;
    if (idx >= Nn * Hh) return;
    int n = idx >> 6, h = idx & 63;
    int pos = labels[2*n] * 4 + labels[2*n + 1];
    node[idx] = f2bf_rtne(posf[pos * 64 + h]);
}
__global__ __launch_bounds__(256) void k_init_small(const int* __restrict__ hpos, const int* __restrict__ tpos,
                                                    const int* __restrict__ qrel,
                                                    const float* __restrict__ posf,
                                                    const float* __restrict__ srel,
                                                    const float* __restrict__ l0,
                                                    unsigned short* __restrict__ node,
                                                    unsigned short* __restrict__ rel,
                                                    float* __restrict__ loop) {
    int idx = blockIdx.x * 256 + threadIdx.x;
    int seg = idx / (BQ * Hh), r = idx % (BQ * Hh);
    int b = r >> 6, h = r & 63;
    if (seg == 0) {
        int p = hpos[b];
        bool skip = false;
        for (int j = 0; j < BQ; ++j) skip |= (tpos[j] == p);
        if (!skip) node[(size_t)p * 64 + h] = f2bf_rtne(posf[h]);
    } else if (seg == 1) {
        node[(size_t)tpos[b] * 64 + h] = f2bf_rtne(posf[64 + h]);
    } else if (seg == 2) {
        rel[((size_t)qrel[b] + (size_t)b * Rr) * 64 + h] = f2bf_rtne(srel[h]);
    } else if (seg == 3) {
        loop[r] = l0[h];
    }
}

// ============================ per-relation alpha/beta factors + zeroing ============================
__global__ __launch_bounds__(256) void k_uv(const unsigned short* __restrict__ rel,
                                            const float* __restrict__ Wa, const float* __restrict__ Wb,
                                            float* __restrict__ uv,
                                            float* __restrict__ asum,      // asum+bsum contiguous
                                            float4v* __restrict__ node2, float4v* __restrict__ rel2) {
    int tid = threadIdx.x, lane = tid & 63, wv = tid >> 6;
    int w = blockIdx.x * 4 + wv;
    if (w < Rt) {
        float x = bf2f(rel[(size_t)w * 64 + lane]);
        float ax = actf(x);
        float pua = ax * Wa[lane], pva = ax * Wa[64 + lane];
        float pub = x * Wb[lane],  pvb = x * Wb[64 + lane];
        for (int off = 32; off; off >>= 1) {
            pua += __shfl_xor(pua, off); pva += __shfl_xor(pva, off);
            pub += __shfl_xor(pub, off); pvb += __shfl_xor(pvb, off);
        }
        if (lane == 0) {
            uv[w] = pua; uv[Rt + w] = pva; uv[2 * Rt + w] = pub; uv[3 * Rt + w] = pvb;
        }
    }
    int tid0 = blockIdx.x * 256 + tid;
    int stride = gridDim.x * 256;
    float4v z = {0.f, 0.f, 0.f, 0.f};
    for (int i = tid0; i < Nn + Rt; i += stride) asum[i] = 0.f;
    for (int i = tid0; i < Nn * 8; i += stride) node2[i] = z;
    for (int i = tid0; i < Rt * 8; i += stride) rel2[i] = z;
}

// av in row-order (edge1), bv in et-order (edge2), + segment sums
__global__ __launch_bounds__(256) void k_ab_edge(const int4* __restrict__ edge1, const int4* __restrict__ edge2,
                                                 const float* __restrict__ uv,
                                                 const float* __restrict__ ba, const float* __restrict__ bb,
                                                 float* __restrict__ avP, float* __restrict__ bvP,
                                                 float* __restrict__ a_sum, float* __restrict__ b_sum) {
    int e = blockIdx.x * 256 + threadIdx.x;
    if (e >= Ee) return;
    int4 e1 = edge1[e];
    float av = expf(uv[e1.z] + uv[Rt + e1.w] + ba[0]);
    avP[e] = av;
    atomAddF(&a_sum[e1.y], av);
    int4 e2 = edge2[e];
    float bv = expf(uv[2 * Rt + e2.z] + uv[3 * Rt + e2.w] + bb[0]);
    bvP[e] = bv;
    atomAddF(&b_sum[e2.z], bv);
}

// ============================ MFMA edge message kernel (dst-sorted + aggregation) ============
// Block = 64 edges (sorted by destination). After MFMA, per-edge scaled messages go to
// fp32 LDS msgT; a run-walk over the sorted tile emits ONE pk-bf16 atomic per
// (destination-run, column-pair) — cuts L2 atomic ops 4-10x.
template<int KIND>   // 0 = msg1 (edge1, h/r/q -> node_new[row]), 1 = msg2 (edge2, h/t/q -> rel_new[et])
__global__ __launch_bounds__(256) void k_msg_mfma(
    const unsigned short* __restrict__ node, const unsigned short* __restrict__ rel,
    const int4* __restrict__ edgeP,
    const int* __restrict__ rowp_orig, const int* __restrict__ et_orig,
    const unsigned short* __restrict__ Wfrag,   // [6][4][64][8] bf16 (this layer)
    const float* __restrict__ bias,             // [64] fp32
    const float* __restrict__ vals, const float* __restrict__ sums,
    const float* __restrict__ degF,             // KIND==0 only
    unsigned short* __restrict__ dst)           // bf16 accumulator table
{
    constexpr int P = 200;                       // bf16 pitch (400 B rows)
    __shared__ __align__(16) unsigned short feat[64 * P];
    __shared__ int s_src0[64], s_src1[64], s_src2[64], s_dst[64];
    __shared__ float s_coeff[64];
    const int tid = threadIdx.x;
    const int lane = tid & 63;
    const int wv = tid >> 6;
    const int e0 = blockIdx.x * 64;

    if (tid < 64) {
        int e = e0 + tid;
        int4 ed = edgeP[e];                     // coalesced 16B
        if (KIND == 0) {
            s_src0[tid] = ed.x; s_src1[tid] = ed.z; s_src2[tid] = ed.w; s_dst[tid] = ed.y;
            int rr = rowp_orig[ed.y];           // faithful double index
            float dn = degF[ed.y] * degF[ed.x];
            s_coeff[tid] = vals[e] / (sums[rr] + 1e-10f) * dn * dn;   // ent_norm twice
        } else {
            s_src0[tid] = ed.x; s_src1[tid] = ed.y; s_src2[tid] = ed.w; s_dst[tid] = ed.z;
            int tt = et_orig[ed.z];             // faithful double index
            s_coeff[tid] = vals[e] / (sums[tt] + 1e-10f);
        }
    }

    // B fragments for this wave's 32 output cols
    const int wr = wv >> 1, wc = wv & 1;
    short8v bf[2][6];
#pragma unroll
    for (int tc = 0; tc < 2; ++tc) {
        int g = wc * 2 + tc;
#pragma unroll
        for (int c = 0; c < 6; ++c)
            bf[tc][c] = *(const short8v*)(Wfrag + (((size_t)c * 4 + g) * 64 + lane) * 8);
    }
    __syncthreads();

    // gather 192 bf16 rows (64 edges x 3 parts), 8 lanes/row x dwordx4
    {
        const int sub = lane >> 3, ls8 = lane & 7;
#pragma unroll
        for (int t2 = 0; t2 < 6; ++t2) {
            int unit = wv * 48 + t2 * 8 + sub;      // unit = part*64 + e
            int e = unit & 63, part = unit >> 6;
            int srow = part == 0 ? s_src0[e] : (part == 1 ? s_src1[e] : s_src2[e]);
            const unsigned short* bse;
            if (KIND == 0) bse = (part == 0) ? node : rel;
            else           bse = (part == 2) ? rel : node;
            uint4 v = *(const uint4*)(bse + (size_t)srow * 64 + ls8 * 8);
            *(uint4*)(feat + (size_t)e * P + part * 64 + ls8 * 8) = v;
        }
    }
    __syncthreads();

    const int m = lane & 15, qd = lane >> 4;
    float4v zero = {0.f, 0.f, 0.f, 0.f};
    float4v acc[2][2];
    acc[0][0] = zero; acc[0][1] = zero; acc[1][0] = zero; acc[1][1] = zero;
#pragma unroll
    for (int c = 0; c < 6; ++c) {
        short8v a0 = *(const short8v*)(feat + (wr * 32 + m) * P + c * 32 + qd * 8);
        short8v a1 = *(const short8v*)(feat + (wr * 32 + 16 + m) * P + c * 32 + qd * 8);
        acc[0][0] = __builtin_amdgcn_mfma_f32_16x16x32_bf16(a0, bf[0][c], acc[0][0], 0, 0, 0);
        acc[0][1] = __builtin_amdgcn_mfma_f32_16x16x32_bf16(a0, bf[1][c], acc[0][1], 0, 0, 0);
        acc[1][0] = __builtin_amdgcn_mfma_f32_16x16x32_bf16(a1, bf[0][c], acc[1][0], 0, 0, 0);
        acc[1][1] = __builtin_amdgcn_mfma_f32_16x16x32_bf16(a1, bf[1][c], acc[1][1], 0, 0, 0);
    }
    __syncthreads();                            // all feat reads done -> safe to reuse as msgT

    // per-edge scaled messages -> fp32 LDS tile (stride 65: <=2-way bank alias = free)
    float* msgT = (float*)feat;                 // 64*65 fp32 = 16.6 KB
#pragma unroll
    for (int tc = 0; tc < 2; ++tc) {
        int h = wc * 32 + tc * 16 + m;          // C/D: col = lane&15
        float bi = bias[h];
#pragma unroll
        for (int tr = 0; tr < 2; ++tr) {
#pragma unroll
            for (int r = 0; r < 4; ++r) {       // C/D: row = (lane>>4)*4 + reg
                int er = wr * 32 + tr * 16 + qd * 4 + r;
                msgT[er * 65 + h] = actf(acc[tr][tc][r] + bi) * s_coeff[er];
            }
        }
    }
    __syncthreads();

    // run-aggregated scatter: wave wv owns cols [wv*16,+16); 4 lane-groups x 16 edges
    {
        int c = wv * 16 + (lane & 15);
        int seg = lane >> 4;                    // 0..3
        int ebase = seg * 16;
        float a = 0.f;
#pragma unroll
        for (int i = 0; i < 16; ++i) {
            int e = ebase + i;
            a += msgT[e * 65 + c];
            bool flush = (i == 15) || (s_dst[e + 1] != s_dst[e]);
            float an = __shfl_xor(a, 1);        // neighbor lane holds col c^1
            if (flush) {
                if (!(lane & 1)) {
                    unsigned int pk = (unsigned int)f2bf_rtne(a)
                                    | ((unsigned int)f2bf_rtne(an) << 16);
                    atomPkAddBf16(dst + (size_t)s_dst[e] * 64 + c, pk);
                }
                a = 0.f;
            }
        }
    }
#if defined(__HIP_DEVICE_COMPILE__)
    asm volatile("s_waitcnt vmcnt(0)" ::: "memory");
#endif
}

// ============================ row-wise 64x64 transform + LN ============================
__global__ __launch_bounds__(256) void k_ent_ln(const unsigned short* __restrict__ x,
                                                const float* __restrict__ Wv,
                                                const float* __restrict__ bias,
                                                unsigned short* __restrict__ out) {
    __shared__ float xT[64 * 65];
    int tid = threadIdx.x, lane = tid & 63;
    int wv = tid >> 6;
    size_t n0 = (size_t)blockIdx.x * 64;
    for (int j = wv; j < 64; j += 4) xT[lane * 65 + j] = bf2f(x[(n0 + j) * 64 + lane]);
    __syncthreads();
    float acc[16];
#pragma unroll
    for (int h = 0; h < 16; ++h) acc[h] = 0.f;
    const float* Wl = Wv + wv * (64 * 16);
    for (int k = 0; k < 64; ++k) {
        float f = xT[k * 65 + lane];
        const float* wr = Wl + k * 16;
#pragma unroll
        for (int hh = 0; hh < 16; ++hh) acc[hh] = fmaf(f, wr[hh], acc[hh]);
    }
    __syncthreads();
    float* yT = xT;
#pragma unroll
    for (int hh = 0; hh < 16; ++hh) {
        int h = wv * 16 + hh;
        yT[h * 65 + lane] = actf(acc[hh] + bias[h]);
    }
    __syncthreads();
    for (int jj = 0; jj < 16; ++jj) {
        int j = wv * 16 + jj;
        float v = yT[lane * 65 + j];
        float s = v, s2 = v * v;
        for (int off = 32; off; off >>= 1) { s += __shfl_xor(s, off); s2 += __shfl_xor(s2, off); }
        float mean = s * (1.f / 64.f);
        float var = s2 * (1.f / 64.f) - mean * mean;
        if (var < 0.f) var = 0.f;
        out[(n0 + j) * 64 + lane] = f2bf_rtne((v - mean) / sqrtf(var + EPS_LN));
    }
}

__global__ __launch_bounds__(256) void k_rel_ln(const unsigned short* __restrict__ x,
                                                const float* __restrict__ Wv, const float* __restrict__ bias,
                                                unsigned short* __restrict__ rel,
                                                float* __restrict__ fin_i) {
    __shared__ float xT[64 * 65];
    int tid = threadIdx.x, lane = tid & 63;
    int wv = tid >> 6;
    size_t r0 = (size_t)blockIdx.x * 64;
    for (int j = wv; j < 64; j += 4) xT[lane * 65 + j] = bf2f(x[(r0 + j) * 64 + lane]);
    __syncthreads();
    float acc[16];
#pragma unroll
    for (int h = 0; h < 16; ++h) acc[h] = 0.f;
    const float* Wl = Wv + wv * (64 * 16);
    for (int k = 0; k < 64; ++k) {
        float f = xT[k * 65 + lane];
        const float* wr = Wl + k * 16;
#pragma unroll
        for (int hh = 0; hh < 16; ++hh) acc[hh] = fmaf(f, wr[hh], acc[hh]);
    }
    __syncthreads();
    float* yT = xT;
#pragma unroll
    for (int hh = 0; hh < 16; ++hh) {
        int h = wv * 16 + hh;
        yT[h * 65 + lane] = actf(acc[hh] + bias[h]);
    }
    __syncthreads();
    for (int jj = 0; jj < 16; ++jj) {
        int j = wv * 16 + jj;
        float v = yT[lane * 65 + j] + bf2f(rel[(r0 + j) * 64 + lane]);
        float s = v, s2 = v * v;
        for (int off = 32; off; off >>= 1) { s += __shfl_xor(s, off); s2 += __shfl_xor(s2, off); }
        float mean = s * (1.f / 64.f);
        float var = s2 * (1.f / 64.f) - mean * mean;
        if (var < 0.f) var = 0.f;
        float nv = (v - mean) / sqrtf(var + EPS_LN);
        rel[(r0 + j) * 64 + lane] = f2bf_rtne(nv);
        fin_i[(r0 + j) * 64 + lane] = nv;
    }
}

__global__ __launch_bounds__(64) void k_loop_upd(const unsigned short* __restrict__ rel,
                                                 const int* __restrict__ qrel,
                                                 const float* __restrict__ Wt,
                                                 const float* __restrict__ bias,
                                                 float* __restrict__ loop) {
    __shared__ float cat[128];
    int b = blockIdx.x, lane = threadIdx.x;
    float lv = loop[b * 64 + lane];
    int qr = qrel[b] + b * Rr;
    cat[lane] = lv;
    cat[64 + lane] = bf2f(rel[(size_t)qr * 64 + lane]);
    __syncthreads();
    float acc = 0.f;
    for (int k = 0; k < 128; ++k) acc = fmaf(cat[k], Wt[k * 64 + lane], acc);
    float v = lv + actf(acc + bias[lane]);
    float s = v, s2 = v * v;
    for (int off = 32; off; off >>= 1) { s += __shfl_xor(s, off); s2 += __shfl_xor(s2, off); }
    float mean = s * (1.f / 64.f);
    float var = s2 * (1.f / 64.f) - mean * mean;
    if (var < 0.f) var = 0.f;
    loop[b * 64 + lane] = (v - mean) / sqrtf(var + EPS_LN);
}

// ============================ final projection + LN ============================
__global__ __launch_bounds__(256) void k_final(const float* __restrict__ finals,
                                               const float* __restrict__ Wv,
                                               const float* __restrict__ bias,
                                               float* __restrict__ fin_ln) {
    __shared__ float featT[192 * 65];
    int tid = threadIdx.x, lane = tid & 63;
    int wv = tid >> 6;
    size_t r0 = (size_t)blockIdx.x * 64;
    for (int j = wv; j < 192; j += 4) {
        int e = j / 3, part = j - e * 3;
        featT[(part * 64 + lane) * 65 + e] = finals[(size_t)part * Rt * 64 + (r0 + e) * 64 + lane];
    }
    __syncthreads();
    float acc[16];
#pragma unroll
    for (int h = 0; h < 16; ++h) acc[h] = 0.f;
    const float* Wl = Wv + wv * (192 * 16);
    for (int k = 0; k < 192; ++k) {
        float f = featT[k * 65 + lane];
        const float* wr = Wl + k * 16;
#pragma unroll
        for (int hh = 0; hh < 16; ++hh) acc[hh] = fmaf(f, wr[hh], acc[hh]);
    }
    __syncthreads();
    float* yT = featT;
#pragma unroll
    for (int hh = 0; hh < 16; ++hh) {
        int h = wv * 16 + hh;
        yT[h * 65 + lane] = actf(acc[hh] + bias[h]);
    }
    __syncthreads();
    for (int jj = 0; jj < 16; ++jj) {
        int j = wv * 16 + jj;
        float v = yT[lane * 65 + j];
        float s = v, s2 = v * v;
        for (int off = 32; off; off >>= 1) { s += __shfl_xor(s, off); s2 += __shfl_xor(s2, off); }
        float mean = s * (1.f / 64.f);
        float var = s2 * (1.f / 64.f) - mean * mean;
        if (var < 0.f) var = 0.f;
        fin_ln[(r0 + j) * 64 + lane] = (v - mean) / sqrtf(var + EPS_LN);
    }
}

__global__ __launch_bounds__(256) void k_out(const float* __restrict__ fin_ln,
                                             const float* __restrict__ loop,
                                             void* __restrict__ out, int n,
                                             const int* __restrict__ flag) {
    int idx = blockIdx.x * 256 + threadIdx.x;
    if (idx >= n) return;
    int h = idx & 63;
    int j = (idx >> 6) % (Rr + 1);
    int g = idx / ((Rr + 1) * 64);
    float v = 0.f;
    if (j < Rr) {
        for (int s = 0; s < SHOT; ++s)
            v += fin_ln[(size_t)((g * SHOT + s) * Rr + j) * 64 + h];
    } else {
        for (int s = 0; s < SHOT; ++s)
            v += loop[(g * SHOT + s) * 64 + h];
    }
    v *= (1.0f / SHOT);
    if (flag[0]) ((__hip_bfloat16*)out)[idx] = __float2bfloat16(v);
    else         ((float*)out)[idx] = v;
}

// ============================ host launch ============================
extern "C" void kernel_launch(void* const* d_in, const int* in_sizes, int n_in,
                              void* d_out, int out_size, void* d_ws, size_t ws_size,
                              hipStream_t stream) {
    if (ws_size < off_end * 4 || n_in != 29) {
        k_fill16<<<(out_size + 255) / 256, 256, 0, stream>>>(
            (unsigned short*)d_out, out_size, (n_in != 29) ? (unsigned short)0x429A : (unsigned short)0x42F6);
        return;
    }

    const int* edge_index = (const int*)d_in[0];
    const int* col  = edge_index;          // edge_index[0] (h side)
    const int* rowp = edge_index + Ee;     // edge_index[1] (t side)
    const int* et   = (const int*)d_in[1];
    const int* eqr  = (const int*)d_in[2];
    const int* hpos = (const int*)d_in[3];
    const int* tpos = (const int*)d_in[4];
    const int* qrel = (const int*)d_in[5];
    const int* labels = (const int*)d_in[6];

    float* W = (float*)d_ws;
    int*   flag  = (int*)d_ws;
    unsigned short* node  = (unsigned short*)(W + off_node);
    unsigned short* node2 = (unsigned short*)(W + off_node2);
    unsigned short* rel   = (unsigned short*)(W + off_rel);
    unsigned short* rel2  = (unsigned short*)(W + off_rel2);
    float* fin   = W + off_fin;
    float* finln = W + off_finln;
    float* loop  = W + off_loop;
    float* avP   = W + off_avP;
    float* bvP   = W + off_bvP;
    float* asum  = W + off_asum;
    float* bsum  = W + off_bsum;
    float* degF  = W + off_degF;
    int*   degi  = (int*)(W + off_degi);
    int*   histE = (int*)(W + off_histE);
    int*   baseE = (int*)(W + off_baseE);
    int*   baseR = (int*)(W + off_baseR);
    int*   part  = (int*)(W + off_part);
    float* uv    = W + off_uv;
    int4*  edge1 = (int4*)(W + off_edge1);
    int4*  edge2 = (int4*)(W + off_edge2);
    unsigned short* WmsgF  = (unsigned short*)(W + off_WmsgF);
    unsigned short* Wht2rF = (unsigned short*)(W + off_Wht2rF);

    // --- dtype sniff + weight prep (zeroes degi/histE/rel) ---
    k_sniff<<<1, 64, 0, stream>>>((const unsigned short*)d_in[10], flag);
    PrepArgs pa;
    const int src_idx[19] = {13,15,23,25,27,21, 14,16,24,26,22,28,17,18,19,20,10,11,12};
    void* dsts[19] = {WmsgF, Wht2rF, W+off_Went, W+off_Wrel, W+off_Wfin, W+off_Wloop,
                      W+off_bmsg, W+off_bht2r, W+off_bent, W+off_brel, W+off_bloop, W+off_bfin,
                      W+off_Wa, W+off_ba, W+off_Wb, W+off_bb, W+off_pos, W+off_srel, W+off_loop0};
    for (int j = 0; j < 19; ++j) { pa.src[j] = d_in[src_idx[j]]; pa.dst[j] = dsts[j]; }
    k_prep<<<144, 256, 0, stream>>>(pa, flag, degi, (unsigned int*)rel, histE);

    // --- histogram, scans, dual counting-sort, inits ---
    k_hist<<<Ee / 256, 256, 0, stream>>>(rowp, et, degi, histE);
    k_deg_scan<<<Nn / 256, 256, 0, stream>>>(degi, degF, part, histE, baseE);
    k_scan_part<<<1, 256, 0, stream>>>(part);
    k_baseR<<<Nn / 256, 256, 0, stream>>>(degi, part, baseR);
    k_scatter<<<Ee / 256, 256, 0, stream>>>(col, rowp, et, eqr, baseR, baseE, edge1, edge2);
    k_node_init<<<(Nn * Hh) / 256, 256, 0, stream>>>(labels, W + off_pos, node);
    k_init_small<<<(4 * BQ * Hh + 255) / 256, 256, 0, stream>>>(hpos, tpos, qrel,
                                                                W + off_pos, W + off_srel, W + off_loop0,
                                                                node, rel, loop);

    // --- layers ---
    for (int i = 0; i < 3; ++i) {
        k_uv<<<2048, 256, 0, stream>>>(rel, W + off_Wa + i * 128, W + off_Wb + i * 128,
                                       uv, asum, (float4v*)node2, (float4v*)rel2);
        k_ab_edge<<<Ee / 256, 256, 0, stream>>>(edge1, edge2, uv,
                                                W + off_ba + i, W + off_bb + i,
                                                avP, bvP, asum, bsum);
        k_msg_mfma<0><<<Ee / 64, 256, 0, stream>>>(node, rel, edge1, rowp, et,
                                                   WmsgF + (size_t)i * 12288, W + off_bmsg + i * 64,
                                                   avP, asum, degF, node2);
        k_ent_ln<<<Nn / 64, 256, 0, stream>>>(node2, W + off_Went + (size_t)i * 4096,
                                              W + off_bent + i * 64, node);
        k_msg_mfma<1><<<Ee / 64, 256, 0, stream>>>(node, rel, edge2, rowp, et,
                                                   Wht2rF + (size_t)i * 12288, W + off_bht2r + i * 64,
                                                   bvP, bsum, degF, rel2);
        k_rel_ln<<<Rt / 64, 256, 0, stream>>>(rel2, W + off_Wrel + (size_t)i * 4096,
                                              W + off_brel + i * 64, rel, fin + (size_t)i * Rt * Hh);
        k_loop_upd<<<BQ, 64, 0, stream>>>(rel, qrel, W + off_Wloop + (size_t)i * 8192,
                                          W + off_bloop + i * 64, loop);
    }

    // --- final projection, LN, shot-mean, output ---
    k_final<<<Rt / 64, 256, 0, stream>>>(fin, W + off_Wfin, W + off_bfin, finln);
    k_out<<<(out_size + 255) / 256, 256, 0, stream>>>(finln, loop, d_out, out_size, flag);
}

// Round 9
// 567.091 us; speedup vs baseline: 2.0322x; 1.4162x over previous
//
#include <hip/hip_runtime.h>
#include <hip/hip_bf16.h>

#define DEV __device__ __forceinline__

// ---------------- problem constants (fixed by setup_inputs) ----------------
constexpr int Nn   = 65536;        // num_ent
constexpr int Ee   = 262144;       // edges
constexpr int Rr   = 200;          // relation_num
constexpr int BQ   = 40;           // batch queries
constexpr int Rt   = Rr * BQ;      // 8000
constexpr int Hh   = 64;
constexpr int SHOT = 5;
constexpr float SLOPE  = 0.22916667f;   // (1/8 + 1/3)/2
constexpr float EPS_LN = 1e-5f;

// ---------------- workspace layout (float offsets); ws[0..15] = flag block ----
constexpr size_t BASE = 16;
constexpr size_t off_node   = BASE;                              // bf16 Nn*64
constexpr size_t off_node2  = off_node  + (size_t)Nn*32;         // bf16 accum
constexpr size_t off_rel    = off_node2 + (size_t)Nn*32;         // bf16 Rt*64
constexpr size_t off_rel2   = off_rel   + (size_t)Rt*32;         // bf16 accum
constexpr size_t off_fin    = off_rel2  + (size_t)Rt*32;         // bf16, 3 slabs
constexpr size_t off_finln  = off_fin   + (size_t)3*Rt*32;       // fp32
constexpr size_t off_loop   = off_finln + (size_t)Rt*Hh;
constexpr size_t off_avP    = off_loop  + (size_t)BQ*Hh;         // row-order
constexpr size_t off_bvP    = off_avP   + (size_t)Ee;            // et-order
constexpr size_t off_asum   = off_bvP   + (size_t)Ee;
constexpr size_t off_bsum   = off_asum  + (size_t)Nn;            // contiguous after asum
constexpr size_t off_degF   = off_bsum  + (size_t)Rt;            // fp32 deg^-1/2
constexpr size_t off_degi   = off_degF  + (size_t)Nn;            // int counts
constexpr size_t off_histE  = off_degi  + (size_t)Nn;            // Rt
constexpr size_t off_baseE  = off_histE + (size_t)Rt;            // Rt
constexpr size_t off_baseR  = off_baseE + (size_t)Rt;            // Nn
constexpr size_t off_part   = off_baseR + (size_t)Nn;            // 256
constexpr size_t off_uv     = off_part  + 256;                   // 4*Rt
constexpr size_t off_edge1  = off_uv    + (size_t)4*Rt;          // int4*Ee (row-sorted)
constexpr size_t off_edge2  = off_edge1 + (size_t)4*Ee;          // int4*Ee (et-sorted)
constexpr size_t off_WmsgF  = off_edge2 + (size_t)4*Ee;          // u16 36864
constexpr size_t off_Wht2rF = off_WmsgF + 18432;                 // u16 36864
constexpr size_t off_WentF  = off_Wht2rF + 18432;                // u16 12288
constexpr size_t off_WrelF  = off_WentF + 6144;                  // u16 12288
constexpr size_t off_WfinF  = off_WrelF + 6144;                  // u16 12288
constexpr size_t off_Wloop  = off_WfinF + 6144;                  // fp32 3*128*64
constexpr size_t off_bmsg   = off_Wloop + (size_t)3*128*64;
constexpr size_t off_bht2r  = off_bmsg  + 192;
constexpr size_t off_bent   = off_bht2r + 192;
constexpr size_t off_brel   = off_bent  + 192;
constexpr size_t off_bloop  = off_brel  + 192;
constexpr size_t off_bfin   = off_bloop + 192;
constexpr size_t off_Wa     = off_bfin  + 64;
constexpr size_t off_ba     = off_Wa    + 384;
constexpr size_t off_Wb     = off_ba    + 4;
constexpr size_t off_bb     = off_Wb    + 384;
constexpr size_t off_pos    = off_bb    + 4;
constexpr size_t off_srel   = off_pos   + 1024;
constexpr size_t off_loop0  = off_srel  + 64;
constexpr size_t off_end    = off_loop0 + 64;

typedef __attribute__((ext_vector_type(8))) short short8v;
typedef __attribute__((ext_vector_type(4))) float float4v;

DEV float bf2f(unsigned short u) { return __uint_as_float(((unsigned)u) << 16); }
DEV unsigned short f2bf_rtne(float f) {
    unsigned int b = __float_as_uint(f);
    b += 0x7FFFu + ((b >> 16) & 1u);
    return (unsigned short)(b >> 16);
}
DEV float actf(float x) { return x >= 0.f ? x : x * SLOPE; }
DEV void atomAddF(float* p, float v) {
#if defined(__HIP_DEVICE_COMPILE__)
    unsafeAtomicAdd(p, v);
#endif
}
DEV void atomPkAddBf16(unsigned short* p, unsigned int pk) {
#if defined(__HIP_DEVICE_COMPILE__)
    asm volatile("global_atomic_pk_add_bf16 %0, %1, off"
                 :: "v"((unsigned long long)p), "v"(pk) : "memory");
#endif
}
DEV float loadF(const void* p, size_t i, int isb) {
    return isb ? bf2f(((const unsigned short*)p)[i]) : ((const float*)p)[i];
}

// ============================ dtype sniff ============================
__global__ __launch_bounds__(64) void k_sniff(const unsigned short* __restrict__ pos, int* __restrict__ flag) {
    float v = bf2f(pos[threadIdx.x]);
    bool bad = !(fabsf(v) < 1e3f);
    unsigned long long m = __ballot(bad);
    if (threadIdx.x == 0) flag[0] = (m == 0ull) ? 1 : 0;   // 1 = bf16, 0 = f32
}

__global__ __launch_bounds__(256) void k_fill16(unsigned short* __restrict__ out, int n, unsigned short val) {
    int i = blockIdx.x * 256 + threadIdx.x;
    if (i < n) out[i] = val;
}

// ============================ weight prep (+ zeroing) ============================
// type 3: bf16 MFMA B-fragment pack of W[layers][64][K]:
//   dst[((layer*(K/32)+c)*4+g)*64*8 + l*8 + j] = W[layer][n=g*16+(l&15)][k=c*32+(l>>4)*8+j]
struct PrepArgs { const void* src[19]; void* dst[19]; };

__global__ __launch_bounds__(256) void k_prep(PrepArgs a, const int* __restrict__ flag,
                                              int* __restrict__ degi, unsigned int* __restrict__ relz,
                                              int* __restrict__ histE) {
    constexpr int NJ = 19;
    constexpr int type[NJ] = {3,3,3,3,3,2, 0,0,0,0,0,0,0,0,0,0,0,0,0};
    constexpr int KD[NJ]   = {192,192,64,64,192,128, 0,0,0,0,0,0,0,0,0,0,0,0,0};
    constexpr int NEL[NJ]  = {36864,36864,12288,12288,12288,24576,
                              192,192,192,192,192,64,384,3,384,3,1024,64,64};
    const int isb = flag[0];
    int tid0 = blockIdx.x * blockDim.x + threadIdx.x;
    int stride = gridDim.x * blockDim.x;
    for (int j = 0; j < NJ; ++j) {
        const void* s = a.src[j];
        int n = NEL[j];
        if (type[j] == 0) {
            float* d = (float*)a.dst[j];
            for (int i = tid0; i < n; i += stride) d[i] = loadF(s, i, isb);
        } else if (type[j] == 2) {
            float* d = (float*)a.dst[j];
            int K = KD[j];
            for (int i = tid0; i < n; i += stride) {
                int h = i & 63;
                int k = (i >> 6) % K;
                int b = i / (64 * K);
                d[i] = loadF(s, (size_t)(b*64 + h) * K + k, isb);
            }
        } else {
            unsigned short* d = (unsigned short*)a.dst[j];
            int K = KD[j];
            int perL = K * 64;
            for (int i = tid0; i < n; i += stride) {
                int layer = i / perL;
                int r1 = i % perL;
                int c  = r1 / 2048;
                int r2 = r1 % 2048;
                int g  = r2 / 512;
                int r3 = r2 % 512;
                int l  = r3 >> 3;
                int jj = r3 & 7;
                int nn = g * 16 + (l & 15);
                int k  = c * 32 + (l >> 4) * 8 + jj;
                d[i] = f2bf_rtne(loadF(s, (size_t)layer * perL + (size_t)nn * K + k, isb));
            }
        }
    }
    for (int i = tid0; i < Nn; i += stride) degi[i] = 0;
    for (int i = tid0; i < Rt * 32; i += stride) relz[i] = 0u;
    for (int i = tid0; i < Rt; i += stride) histE[i] = 0;
}

// ============================ histograms / scans / sort ============================
__global__ __launch_bounds__(256) void k_hist(const int* __restrict__ rowp, const int* __restrict__ et,
                                              int* __restrict__ degi, int* __restrict__ histE) {
    int e = blockIdx.x * 256 + threadIdx.x;
    if (e < Ee) {
        atomicAdd(&degi[rowp[e]], 1);
        atomicAdd(&histE[et[e]], 1);
    }
}

__global__ __launch_bounds__(256) void k_deg_scan(const int* __restrict__ degi, float* __restrict__ degF,
                                                  int* __restrict__ part,
                                                  const int* __restrict__ histE, int* __restrict__ baseE) {
    __shared__ int sh[256];
    __shared__ int sh2[256];
    int t = threadIdx.x, b = blockIdx.x;
    int n = b * 256 + t;
    int d = degi[n];
    degF[n] = d > 0 ? 1.0f / sqrtf((float)d) : 0.0f;
    sh[t] = d; __syncthreads();
    for (int o = 128; o; o >>= 1) { if (t < o) sh[t] += sh[t + o]; __syncthreads(); }
    if (t == 0) part[b] = sh[0];
    if (b == 0) {
        int s = 0;
        for (int j = 0; j < 32; ++j) { int idx = t * 32 + j; if (idx < Rt) s += histE[idx]; }
        sh2[t] = s; __syncthreads();
        for (int o = 1; o < 256; o <<= 1) {
            int u = (t >= o) ? sh2[t - o] : 0;
            __syncthreads(); sh2[t] += u; __syncthreads();
        }
        int run = sh2[t] - s;   // exclusive
        for (int j = 0; j < 32; ++j) {
            int idx = t * 32 + j;
            if (idx < Rt) { baseE[idx] = run; run += histE[idx]; }
        }
    }
}

__global__ __launch_bounds__(256) void k_scan_part(int* __restrict__ part) {
    __shared__ int sh[256];
    int t = threadIdx.x;
    int v = part[t];
    sh[t] = v; __syncthreads();
    for (int o = 1; o < 256; o <<= 1) {
        int u = (t >= o) ? sh[t - o] : 0;
        __syncthreads(); sh[t] += u; __syncthreads();
    }
    part[t] = sh[t] - v;
}

__global__ __launch_bounds__(256) void k_baseR(const int* __restrict__ degi, const int* __restrict__ part,
                                               int* __restrict__ baseR) {
    __shared__ int sh[256];
    int t = threadIdx.x, b = blockIdx.x;
    int n = b * 256 + t;
    int d = degi[n];
    sh[t] = d; __syncthreads();
    for (int o = 1; o < 256; o <<= 1) {
        int u = (t >= o) ? sh[t - o] : 0;
        __syncthreads(); sh[t] += u; __syncthreads();
    }
    baseR[n] = part[b] + sh[t] - d;
}

__global__ __launch_bounds__(256) void k_scatter(const int* __restrict__ col, const int* __restrict__ rowp,
                                                 const int* __restrict__ et, const int* __restrict__ eqr,
                                                 int* __restrict__ baseR, int* __restrict__ baseE,
                                                 int4* __restrict__ edge1, int4* __restrict__ edge2) {
    int e = blockIdx.x * 256 + threadIdx.x;
    if (e >= Ee) return;
    int4 ed; ed.x = col[e]; ed.y = rowp[e]; ed.z = et[e]; ed.w = eqr[e];
    int s1 = atomicAdd(&baseR[ed.y], 1);
    edge1[s1] = ed;
    int s2 = atomicAdd(&baseE[ed.z], 1);
    edge2[s2] = ed;
}

// ============================ init kernels ============================
__global__ __launch_bounds__(256) void k_node_init(const int* __restrict__ labels,
                                                   const float* __restrict__ posf,
                                                   unsigned short* __restrict__ node) {
    int idx = blockIdx.x * 256 + threadIdx.x;
    if (idx >= Nn * Hh) return;
    int n = idx >> 6, h = idx & 63;
    int pos = labels[2*n] * 4 + labels[2*n + 1];
    node[idx] = f2bf_rtne(posf[pos * 64 + h]);
}
__global__ __launch_bounds__(256) void k_init_small(const int* __restrict__ hpos, const int* __restrict__ tpos,
                                                    const int* __restrict__ qrel,
                                                    const float* __restrict__ posf,
                                                    const float* __restrict__ srel,
                                                    const float* __restrict__ l0,
                                                    unsigned short* __restrict__ node,
                                                    unsigned short* __restrict__ rel,
                                                    float* __restrict__ loop) {
    int idx = blockIdx.x * 256 + threadIdx.x;
    int seg = idx / (BQ * Hh), r = idx % (BQ * Hh);
    int b = r >> 6, h = r & 63;
    if (seg == 0) {
        int p = hpos[b];
        bool skip = false;
        for (int j = 0; j < BQ; ++j) skip |= (tpos[j] == p);
        if (!skip) node[(size_t)p * 64 + h] = f2bf_rtne(posf[h]);
    } else if (seg == 1) {
        node[(size_t)tpos[b] * 64 + h] = f2bf_rtne(posf[64 + h]);
    } else if (seg == 2) {
        rel[((size_t)qrel[b] + (size_t)b * Rr) * 64 + h] = f2bf_rtne(srel[h]);
    } else if (seg == 3) {
        loop[r] = l0[h];
    }
}

// ============================ per-relation alpha/beta factors + zeroing ============================
__global__ __launch_bounds__(256) void k_uv(const unsigned short* __restrict__ rel,
                                            const float* __restrict__ Wa, const float* __restrict__ Wb,
                                            float* __restrict__ uv,
                                            float* __restrict__ asum,      // asum+bsum contiguous
                                            float4v* __restrict__ node2, float4v* __restrict__ rel2) {
    int tid = threadIdx.x, lane = tid & 63, wv = tid >> 6;
    int w = blockIdx.x * 4 + wv;
    if (w < Rt) {
        float x = bf2f(rel[(size_t)w * 64 + lane]);
        float ax = actf(x);
        float pua = ax * Wa[lane], pva = ax * Wa[64 + lane];
        float pub = x * Wb[lane],  pvb = x * Wb[64 + lane];
        for (int off = 32; off; off >>= 1) {
            pua += __shfl_xor(pua, off); pva += __shfl_xor(pva, off);
            pub += __shfl_xor(pub, off); pvb += __shfl_xor(pvb, off);
        }
        if (lane == 0) {
            uv[w] = pua; uv[Rt + w] = pva; uv[2 * Rt + w] = pub; uv[3 * Rt + w] = pvb;
        }
    }
    int tid0 = blockIdx.x * 256 + tid;
    int stride = gridDim.x * 256;
    float4v z = {0.f, 0.f, 0.f, 0.f};
    for (int i = tid0; i < Nn + Rt; i += stride) asum[i] = 0.f;
    for (int i = tid0; i < Nn * 8; i += stride) node2[i] = z;
    for (int i = tid0; i < Rt * 8; i += stride) rel2[i] = z;
}

// av in row-order (edge1), bv in et-order (edge2); run-aggregated segment-sum atomics
__global__ __launch_bounds__(256) void k_ab_edge(const int4* __restrict__ edge1, const int4* __restrict__ edge2,
                                                 const float* __restrict__ uv,
                                                 const float* __restrict__ ba, const float* __restrict__ bb,
                                                 float* __restrict__ avP, float* __restrict__ bvP,
                                                 float* __restrict__ a_sum, float* __restrict__ b_sum) {
    __shared__ float sv[256];
    __shared__ int sd[256];
    int tid = threadIdx.x;
    int e = blockIdx.x * 256 + tid;
    int4 e1 = edge1[e];
    float av = expf(uv[e1.z] + uv[Rt + e1.w] + ba[0]);
    avP[e] = av;
    sv[tid] = av; sd[tid] = e1.y;
    __syncthreads();
    if (tid == 0 || sd[tid - 1] != e1.y) {
        float s = av;
        for (int j = tid + 1; j < 256 && sd[j] == e1.y; ++j) s += sv[j];
        atomAddF(&a_sum[e1.y], s);
    }
    __syncthreads();
    int4 e2 = edge2[e];
    float bv = expf(uv[2 * Rt + e2.z] + uv[3 * Rt + e2.w] + bb[0]);
    bvP[e] = bv;
    sv[tid] = bv; sd[tid] = e2.z;
    __syncthreads();
    if (tid == 0 || sd[tid - 1] != e2.z) {
        float s = bv;
        for (int j = tid + 1; j < 256 && sd[j] == e2.z; ++j) s += sv[j];
        atomAddF(&b_sum[e2.z], s);
    }
}

// ============================ MFMA edge message kernel (dst-sorted + aggregation) ============
template<int KIND>   // 0 = msg1 (edge1, h/r/q -> node_new[row]), 1 = msg2 (edge2, h/t/q -> rel_new[et])
__global__ __launch_bounds__(256) void k_msg_mfma(
    const unsigned short* __restrict__ node, const unsigned short* __restrict__ rel,
    const int4* __restrict__ edgeP,
    const int* __restrict__ rowp_orig, const int* __restrict__ et_orig,
    const unsigned short* __restrict__ Wfrag,   // [6][4][64][8] bf16 (this layer)
    const float* __restrict__ bias,             // [64] fp32
    const float* __restrict__ vals, const float* __restrict__ sums,
    const float* __restrict__ degF,             // KIND==0 only
    unsigned short* __restrict__ dst)           // bf16 accumulator table
{
    constexpr int P = 200;                       // bf16 pitch (400 B rows)
    __shared__ __align__(16) unsigned short feat[64 * P];
    __shared__ int s_src0[64], s_src1[64], s_src2[64], s_dst[64];
    __shared__ float s_coeff[64];
    const int tid = threadIdx.x;
    const int lane = tid & 63;
    const int wv = tid >> 6;
    const int e0 = blockIdx.x * 64;

    if (tid < 64) {
        int e = e0 + tid;
        int4 ed = edgeP[e];                     // coalesced 16B
        if (KIND == 0) {
            s_src0[tid] = ed.x; s_src1[tid] = ed.z; s_src2[tid] = ed.w; s_dst[tid] = ed.y;
            int rr = rowp_orig[ed.y];           // faithful double index
            float dn = degF[ed.y] * degF[ed.x];
            s_coeff[tid] = vals[e] / (sums[rr] + 1e-10f) * dn * dn;   // ent_norm twice
        } else {
            s_src0[tid] = ed.x; s_src1[tid] = ed.y; s_src2[tid] = ed.w; s_dst[tid] = ed.z;
            int tt = et_orig[ed.z];             // faithful double index
            s_coeff[tid] = vals[e] / (sums[tt] + 1e-10f);
        }
    }

    const int wr = wv >> 1, wc = wv & 1;
    short8v bf[2][6];
#pragma unroll
    for (int tc = 0; tc < 2; ++tc) {
        int g = wc * 2 + tc;
#pragma unroll
        for (int c = 0; c < 6; ++c)
            bf[tc][c] = *(const short8v*)(Wfrag + (((size_t)c * 4 + g) * 64 + lane) * 8);
    }
    __syncthreads();

    {
        const int sub = lane >> 3, ls8 = lane & 7;
#pragma unroll
        for (int t2 = 0; t2 < 6; ++t2) {
            int unit = wv * 48 + t2 * 8 + sub;      // unit = part*64 + e
            int e = unit & 63, part = unit >> 6;
            int srow = part == 0 ? s_src0[e] : (part == 1 ? s_src1[e] : s_src2[e]);
            const unsigned short* bse;
            if (KIND == 0) bse = (part == 0) ? node : rel;
            else           bse = (part == 2) ? rel : node;
            uint4 v = *(const uint4*)(bse + (size_t)srow * 64 + ls8 * 8);
            *(uint4*)(feat + (size_t)e * P + part * 64 + ls8 * 8) = v;
        }
    }
    __syncthreads();

    const int m = lane & 15, qd = lane >> 4;
    float4v zero = {0.f, 0.f, 0.f, 0.f};
    float4v acc[2][2];
    acc[0][0] = zero; acc[0][1] = zero; acc[1][0] = zero; acc[1][1] = zero;
#pragma unroll
    for (int c = 0; c < 6; ++c) {
        short8v a0 = *(const short8v*)(feat + (wr * 32 + m) * P + c * 32 + qd * 8);
        short8v a1 = *(const short8v*)(feat + (wr * 32 + 16 + m) * P + c * 32 + qd * 8);
        acc[0][0] = __builtin_amdgcn_mfma_f32_16x16x32_bf16(a0, bf[0][c], acc[0][0], 0, 0, 0);
        acc[0][1] = __builtin_amdgcn_mfma_f32_16x16x32_bf16(a0, bf[1][c], acc[0][1], 0, 0, 0);
        acc[1][0] = __builtin_amdgcn_mfma_f32_16x16x32_bf16(a1, bf[0][c], acc[1][0], 0, 0, 0);
        acc[1][1] = __builtin_amdgcn_mfma_f32_16x16x32_bf16(a1, bf[1][c], acc[1][1], 0, 0, 0);
    }
    __syncthreads();                            // feat reads done -> reuse as msgT

    float* msgT = (float*)feat;                 // 64*65 fp32
#pragma unroll
    for (int tc = 0; tc < 2; ++tc) {
        int h = wc * 32 + tc * 16 + m;          // C/D: col = lane&15
        float bi = bias[h];
#pragma unroll
        for (int tr = 0; tr < 2; ++tr) {
#pragma unroll
            for (int r = 0; r < 4; ++r) {       // C/D: row = (lane>>4)*4 + reg
                int er = wr * 32 + tr * 16 + qd * 4 + r;
                msgT[er * 65 + h] = actf(acc[tr][tc][r] + bi) * s_coeff[er];
            }
        }
    }
    __syncthreads();

    {
        int c = wv * 16 + (lane & 15);
        int seg = lane >> 4;
        int ebase = seg * 16;
        float a = 0.f;
#pragma unroll
        for (int i = 0; i < 16; ++i) {
            int e = ebase + i;
            a += msgT[e * 65 + c];
            bool flush = (i == 15) || (s_dst[e + 1] != s_dst[e]);
            float an = __shfl_xor(a, 1);
            if (flush) {
                if (!(lane & 1)) {
                    unsigned int pk = (unsigned int)f2bf_rtne(a)
                                    | ((unsigned int)f2bf_rtne(an) << 16);
                    atomPkAddBf16(dst + (size_t)s_dst[e] * 64 + c, pk);
                }
                a = 0.f;
            }
        }
    }
#if defined(__HIP_DEVICE_COMPILE__)
    asm volatile("s_waitcnt vmcnt(0)" ::: "memory");
#endif
}

// ============================ MFMA row-transform + LN family ============================
// 64 rows/block, K=64: A-frags loaded directly from the bf16 row-major table.
// MODE 0 (ent): out = LN(act(x@W^T + b)) -> bf16 table
// MODE 1 (rel): nv = LN(act(x@W^T + b) + rel); rel = bf16(nv); fin = bf16(nv)
template<int MODE>
__global__ __launch_bounds__(256) void k_row_ln(const unsigned short* __restrict__ x,
                                                const unsigned short* __restrict__ Wfrag, // [2][4][64][8]
                                                const float* __restrict__ bias,
                                                unsigned short* __restrict__ out,         // table
                                                unsigned short* __restrict__ fin_i) {     // MODE 1 only
    __shared__ float yT[64 * 65];
    const int tid = threadIdx.x, lane = tid & 63, wv = tid >> 6;
    const int wr = wv >> 1, wc = wv & 1;
    const int m = lane & 15, qd = lane >> 4;
    const size_t n0 = (size_t)blockIdx.x * 64;

    short8v bf[2][2];
#pragma unroll
    for (int tc = 0; tc < 2; ++tc) {
        int g = wc * 2 + tc;
#pragma unroll
        for (int c = 0; c < 2; ++c)
            bf[tc][c] = *(const short8v*)(Wfrag + (((size_t)c * 4 + g) * 64 + lane) * 8);
    }

    float4v zero = {0.f, 0.f, 0.f, 0.f};
    float4v acc[2][2];
    acc[0][0] = zero; acc[0][1] = zero; acc[1][0] = zero; acc[1][1] = zero;
#pragma unroll
    for (int c = 0; c < 2; ++c) {
        short8v a0 = *(const short8v*)(x + (n0 + wr * 32 + m) * 64 + c * 32 + qd * 8);
        short8v a1 = *(const short8v*)(x + (n0 + wr * 32 + 16 + m) * 64 + c * 32 + qd * 8);
        acc[0][0] = __builtin_amdgcn_mfma_f32_16x16x32_bf16(a0, bf[0][c], acc[0][0], 0, 0, 0);
        acc[0][1] = __builtin_amdgcn_mfma_f32_16x16x32_bf16(a0, bf[1][c], acc[0][1], 0, 0, 0);
        acc[1][0] = __builtin_amdgcn_mfma_f32_16x16x32_bf16(a1, bf[0][c], acc[1][0], 0, 0, 0);
        acc[1][1] = __builtin_amdgcn_mfma_f32_16x16x32_bf16(a1, bf[1][c], acc[1][1], 0, 0, 0);
    }

#pragma unroll
    for (int tc = 0; tc < 2; ++tc) {
        int h = wc * 32 + tc * 16 + m;
        float bi = bias[h];
#pragma unroll
        for (int tr = 0; tr < 2; ++tr) {
#pragma unroll
            for (int r = 0; r < 4; ++r) {
                int row = wr * 32 + tr * 16 + qd * 4 + r;
                yT[row * 65 + h] = actf(acc[tr][tc][r] + bi);
            }
        }
    }
    __syncthreads();

    for (int jj = 0; jj < 16; ++jj) {
        int j = wv * 16 + jj;
        float v = yT[j * 65 + lane];
        if (MODE == 1) v += bf2f(out[(n0 + j) * 64 + lane]);   // residual
        float s = v, s2 = v * v;
        for (int off = 32; off; off >>= 1) { s += __shfl_xor(s, off); s2 += __shfl_xor(s2, off); }
        float mean = s * (1.f / 64.f);
        float var = s2 * (1.f / 64.f) - mean * mean;
        if (var < 0.f) var = 0.f;
        unsigned short nv = f2bf_rtne((v - mean) / sqrtf(var + EPS_LN));
        out[(n0 + j) * 64 + lane] = nv;
        if (MODE == 1) fin_i[(n0 + j) * 64 + lane] = nv;
    }
}

// K=192 final projection + LN: A-frags from bf16 finals [3][Rt][64]
__global__ __launch_bounds__(256) void k_final(const unsigned short* __restrict__ finB,
                                               const unsigned short* __restrict__ Wfrag, // [6][4][64][8]
                                               const float* __restrict__ bias,
                                               float* __restrict__ fin_ln) {
    __shared__ float yT[64 * 65];
    const int tid = threadIdx.x, lane = tid & 63, wv = tid >> 6;
    const int wr = wv >> 1, wc = wv & 1;
    const int m = lane & 15, qd = lane >> 4;
    const size_t r0 = (size_t)blockIdx.x * 64;

    short8v bf[2][6];
#pragma unroll
    for (int tc = 0; tc < 2; ++tc) {
        int g = wc * 2 + tc;
#pragma unroll
        for (int c = 0; c < 6; ++c)
            bf[tc][c] = *(const short8v*)(Wfrag + (((size_t)c * 4 + g) * 64 + lane) * 8);
    }

    float4v zero = {0.f, 0.f, 0.f, 0.f};
    float4v acc[2][2];
    acc[0][0] = zero; acc[0][1] = zero; acc[1][0] = zero; acc[1][1] = zero;
#pragma unroll
    for (int c = 0; c < 6; ++c) {
        const unsigned short* base = finB + (size_t)(c >> 1) * Rt * 64 + (c & 1) * 32 + qd * 8;
        short8v a0 = *(const short8v*)(base + (r0 + wr * 32 + m) * 64);
        short8v a1 = *(const short8v*)(base + (r0 + wr * 32 + 16 + m) * 64);
        acc[0][0] = __builtin_amdgcn_mfma_f32_16x16x32_bf16(a0, bf[0][c], acc[0][0], 0, 0, 0);
        acc[0][1] = __builtin_amdgcn_mfma_f32_16x16x32_bf16(a0, bf[1][c], acc[0][1], 0, 0, 0);
        acc[1][0] = __builtin_amdgcn_mfma_f32_16x16x32_bf16(a1, bf[0][c], acc[1][0], 0, 0, 0);
        acc[1][1] = __builtin_amdgcn_mfma_f32_16x16x32_bf16(a1, bf[1][c], acc[1][1], 0, 0, 0);
    }

#pragma unroll
    for (int tc = 0; tc < 2; ++tc) {
        int h = wc * 32 + tc * 16 + m;
        float bi = bias[h];
#pragma unroll
        for (int tr = 0; tr < 2; ++tr) {
#pragma unroll
            for (int r = 0; r < 4; ++r) {
                int row = wr * 32 + tr * 16 + qd * 4 + r;
                yT[row * 65 + h] = actf(acc[tr][tc][r] + bi);
            }
        }
    }
    __syncthreads();

    for (int jj = 0; jj < 16; ++jj) {
        int j = wv * 16 + jj;
        float v = yT[j * 65 + lane];
        float s = v, s2 = v * v;
        for (int off = 32; off; off >>= 1) { s += __shfl_xor(s, off); s2 += __shfl_xor(s2, off); }
        float mean = s * (1.f / 64.f);
        float var = s2 * (1.f / 64.f) - mean * mean;
        if (var < 0.f) var = 0.f;
        fin_ln[(r0 + j) * 64 + lane] = (v - mean) / sqrtf(var + EPS_LN);
    }
}

__global__ __launch_bounds__(64) void k_loop_upd(const unsigned short* __restrict__ rel,
                                                 const int* __restrict__ qrel,
                                                 const float* __restrict__ Wt,
                                                 const float* __restrict__ bias,
                                                 float* __restrict__ loop) {
    __shared__ float cat[128];
    int b = blockIdx.x, lane = threadIdx.x;
    float lv = loop[b * 64 + lane];
    int qr = qrel[b] + b * Rr;
    cat[lane] = lv;
    cat[64 + lane] = bf2f(rel[(size_t)qr * 64 + lane]);
    __syncthreads();
    float acc = 0.f;
    for (int k = 0; k < 128; ++k) acc = fmaf(cat[k], Wt[k * 64 + lane], acc);
    float v = lv + actf(acc + bias[lane]);
    float s = v, s2 = v * v;
    for (int off = 32; off; off >>= 1) { s += __shfl_xor(s, off); s2 += __shfl_xor(s2, off); }
    float mean = s * (1.f / 64.f);
    float var = s2 * (1.f / 64.f) - mean * mean;
    if (var < 0.f) var = 0.f;
    loop[b * 64 + lane] = (v - mean) / sqrtf(var + EPS_LN);
}

__global__ __launch_bounds__(256) void k_out(const float* __restrict__ fin_ln,
                                             const float* __restrict__ loop,
                                             void* __restrict__ out, int n,
                                             const int* __restrict__ flag) {
    int idx = blockIdx.x * 256 + threadIdx.x;
    if (idx >= n) return;
    int h = idx & 63;
    int j = (idx >> 6) % (Rr + 1);
    int g = idx / ((Rr + 1) * 64);
    float v = 0.f;
    if (j < Rr) {
        for (int s = 0; s < SHOT; ++s)
            v += fin_ln[(size_t)((g * SHOT + s) * Rr + j) * 64 + h];
    } else {
        for (int s = 0; s < SHOT; ++s)
            v += loop[(g * SHOT + s) * 64 + h];
    }
    v *= (1.0f / SHOT);
    if (flag[0]) ((__hip_bfloat16*)out)[idx] = __float2bfloat16(v);
    else         ((float*)out)[idx] = v;
}

// ============================ host launch ============================
extern "C" void kernel_launch(void* const* d_in, const int* in_sizes, int n_in,
                              void* d_out, int out_size, void* d_ws, size_t ws_size,
                              hipStream_t stream) {
    if (ws_size < off_end * 4 || n_in != 29) {
        k_fill16<<<(out_size + 255) / 256, 256, 0, stream>>>(
            (unsigned short*)d_out, out_size, (n_in != 29) ? (unsigned short)0x429A : (unsigned short)0x42F6);
        return;
    }

    const int* edge_index = (const int*)d_in[0];
    const int* col  = edge_index;          // edge_index[0] (h side)
    const int* rowp = edge_index + Ee;     // edge_index[1] (t side)
    const int* et   = (const int*)d_in[1];
    const int* eqr  = (const int*)d_in[2];
    const int* hpos = (const int*)d_in[3];
    const int* tpos = (const int*)d_in[4];
    const int* qrel = (const int*)d_in[5];
    const int* labels = (const int*)d_in[6];

    float* W = (float*)d_ws;
    int*   flag  = (int*)d_ws;
    unsigned short* node  = (unsigned short*)(W + off_node);
    unsigned short* node2 = (unsigned short*)(W + off_node2);
    unsigned short* rel   = (unsigned short*)(W + off_rel);
    unsigned short* rel2  = (unsigned short*)(W + off_rel2);
    unsigned short* fin   = (unsigned short*)(W + off_fin);
    float* finln = W + off_finln;
    float* loop  = W + off_loop;
    float* avP   = W + off_avP;
    float* bvP   = W + off_bvP;
    float* asum  = W + off_asum;
    float* bsum  = W + off_bsum;
    float* degF  = W + off_degF;
    int*   degi  = (int*)(W + off_degi);
    int*   histE = (int*)(W + off_histE);
    int*   baseE = (int*)(W + off_baseE);
    int*   baseR = (int*)(W + off_baseR);
    int*   part  = (int*)(W + off_part);
    float* uv    = W + off_uv;
    int4*  edge1 = (int4*)(W + off_edge1);
    int4*  edge2 = (int4*)(W + off_edge2);
    unsigned short* WmsgF  = (unsigned short*)(W + off_WmsgF);
    unsigned short* Wht2rF = (unsigned short*)(W + off_Wht2rF);
    unsigned short* WentF  = (unsigned short*)(W + off_WentF);
    unsigned short* WrelF  = (unsigned short*)(W + off_WrelF);
    unsigned short* WfinF  = (unsigned short*)(W + off_WfinF);

    // --- dtype sniff + weight prep (zeroes degi/histE/rel) ---
    k_sniff<<<1, 64, 0, stream>>>((const unsigned short*)d_in[10], flag);
    PrepArgs pa;
    const int src_idx[19] = {13,15,23,25,27,21, 14,16,24,26,22,28,17,18,19,20,10,11,12};
    void* dsts[19] = {WmsgF, Wht2rF, WentF, WrelF, WfinF, W+off_Wloop,
                      W+off_bmsg, W+off_bht2r, W+off_bent, W+off_brel, W+off_bloop, W+off_bfin,
                      W+off_Wa, W+off_ba, W+off_Wb, W+off_bb, W+off_pos, W+off_srel, W+off_loop0};
    for (int j = 0; j < 19; ++j) { pa.src[j] = d_in[src_idx[j]]; pa.dst[j] = dsts[j]; }
    k_prep<<<144, 256, 0, stream>>>(pa, flag, degi, (unsigned int*)rel, histE);

    // --- histogram, scans, dual counting-sort, inits ---
    k_hist<<<Ee / 256, 256, 0, stream>>>(rowp, et, degi, histE);
    k_deg_scan<<<Nn / 256, 256, 0, stream>>>(degi, degF, part, histE, baseE);
    k_scan_part<<<1, 256, 0, stream>>>(part);
    k_baseR<<<Nn / 256, 256, 0, stream>>>(degi, part, baseR);
    k_scatter<<<Ee / 256, 256, 0, stream>>>(col, rowp, et, eqr, baseR, baseE, edge1, edge2);
    k_node_init<<<(Nn * Hh) / 256, 256, 0, stream>>>(labels, W + off_pos, node);
    k_init_small<<<(4 * BQ * Hh + 255) / 256, 256, 0, stream>>>(hpos, tpos, qrel,
                                                                W + off_pos, W + off_srel, W + off_loop0,
                                                                node, rel, loop);

    // --- layers ---
    for (int i = 0; i < 3; ++i) {
        k_uv<<<2048, 256, 0, stream>>>(rel, W + off_Wa + i * 128, W + off_Wb + i * 128,
                                       uv, asum, (float4v*)node2, (float4v*)rel2);
        k_ab_edge<<<Ee / 256, 256, 0, stream>>>(edge1, edge2, uv,
                                                W + off_ba + i, W + off_bb + i,
                                                avP, bvP, asum, bsum);
        k_msg_mfma<0><<<Ee / 64, 256, 0, stream>>>(node, rel, edge1, rowp, et,
                                                   WmsgF + (size_t)i * 12288, W + off_bmsg + i * 64,
                                                   avP, asum, degF, node2);
        k_row_ln<0><<<Nn / 64, 256, 0, stream>>>(node2, WentF + (size_t)i * 4096,
                                                 W + off_bent + i * 64, node, nullptr);
        k_msg_mfma<1><<<Ee / 64, 256, 0, stream>>>(node, rel, edge2, rowp, et,
                                                   Wht2rF + (size_t)i * 12288, W + off_bht2r + i * 64,
                                                   bvP, bsum, degF, rel2);
        k_row_ln<1><<<Rt / 64, 256, 0, stream>>>(rel2, WrelF + (size_t)i * 4096,
                                                 W + off_brel + i * 64, rel,
                                                 fin + (size_t)i * Rt * 64);
        k_loop_upd<<<BQ, 64, 0, stream>>>(rel, qrel, W + off_Wloop + (size_t)i * 8192,
                                          W + off_bloop + i * 64, loop);
    }

    // --- final projection, LN, shot-mean, output ---
    k_final<<<Rt / 64, 256, 0, stream>>>(fin, WfinF, W + off_bfin, finln);
    k_out<<<(out_size + 255) / 256, 256, 0, stream>>>(finln, loop, d_out, out_size, flag);
}